// Round 1
// baseline (2181.331 us; speedup 1.0000x reference)
//
#include <hip/hip_runtime.h>
#include <hip/hip_bf16.h>

#define NN 50000
#define NE 800000
// IN = OUT = 64, fan_in = 128

// ---------------- degree / normalization ----------------
__global__ void k_deg_init(float* __restrict__ deg) {
    int i = blockIdx.x * 256 + threadIdx.x;
    if (i < NN) deg[i] = 1.0f;   // self-loop weight
}

__global__ void k_deg_acc(const int* __restrict__ dst, const float* __restrict__ w,
                          float* __restrict__ deg) {
    int e = blockIdx.x * 256 + threadIdx.x;
    if (e < NE) atomicAdd(&deg[dst[e]], w[e]);
}

__global__ void k_dinv(float* __restrict__ deg) {
    int i = blockIdx.x * 256 + threadIdx.x;
    if (i < NN) {
        float d = deg[i];
        deg[i] = (d > 0.f) ? rsqrtf(fmaxf(d, 1e-12f)) : 0.f;
    }
}

__global__ void k_norm(const int* __restrict__ src, const int* __restrict__ dst,
                       const float* __restrict__ w, const float* __restrict__ dinv,
                       float* __restrict__ norm) {
    int e = blockIdx.x * 256 + threadIdx.x;
    if (e < NE) norm[e] = dinv[src[e]] * w[e] * dinv[dst[e]];
}

// ---------------- GEMM: out[N][OUTC] = concat(X, H or H*r) @ W ----------------
// MODE 0: in = [X | H]     MODE 1: in = [X | H * RU[:, :64]]
template <int OUTC, int MODE>
__launch_bounds__(256)
__global__ void k_gemm(const float* __restrict__ X, const float* __restrict__ Hm,
                       const float* __restrict__ RU, const float* __restrict__ W,
                       float* __restrict__ out) {
    constexpr int ROWS = 32;
    __shared__ float wLds[128 * OUTC];
    __shared__ float inLds[ROWS][128];
    const int tid = threadIdx.x;

    for (int i = tid; i < 128 * OUTC; i += 256) wLds[i] = W[i];

    const int row0 = blockIdx.x * ROWS;
    for (int i = tid; i < ROWS * 128; i += 256) {
        int rr = i >> 7, k = i & 127;
        int row = row0 + rr;
        float v = 0.f;
        if (row < NN) {
            if (k < 64) {
                v = X[row * 64 + k];
            } else {
                float h = Hm[row * 64 + (k - 64)];
                if (MODE == 1) h *= RU[row * 128 + (k - 64)];
                v = h;
            }
        }
        inLds[rr][k] = v;
    }
    __syncthreads();

    constexpr int CG = OUTC / 4;        // float4 column groups
    constexpr int RSTEP = 256 / CG;
    const int cg = tid % CG;
    const int rsub = tid / CG;
    const float4* w4 = reinterpret_cast<const float4*>(wLds) + cg;

    for (int rr = rsub; rr < ROWS; rr += RSTEP) {
        int row = row0 + rr;
        if (row >= NN) continue;
        float4 acc = {0.f, 0.f, 0.f, 0.f};
        #pragma unroll 16
        for (int k = 0; k < 128; ++k) {
            float v = inLds[rr][k];
            float4 wv = w4[k * CG];
            acc.x += v * wv.x; acc.y += v * wv.y;
            acc.z += v * wv.z; acc.w += v * wv.w;
        }
        *reinterpret_cast<float4*>(out + (size_t)row * OUTC + cg * 4) = acc;
    }
}

// ---------------- self-loop init: agg = Z * dinv^2 ----------------
template <int OUTC>
__global__ void k_self(const float* __restrict__ Z, const float* __restrict__ dinv,
                       float* __restrict__ agg) {
    int i = blockIdx.x * 256 + threadIdx.x;        // over NN*OUTC/4
    if (i >= NN * (OUTC / 4)) return;
    int row = i / (OUTC / 4);
    float dn = dinv[row];
    dn = dn * dn;
    float4 z = reinterpret_cast<const float4*>(Z)[i];
    float4 o = {z.x * dn, z.y * dn, z.z * dn, z.w * dn};
    reinterpret_cast<float4*>(agg)[i] = o;
}

// ---------------- edge scatter: agg[dst] += Z[src] * norm ----------------
template <int OUTC>
__global__ void k_scatter(const int* __restrict__ src, const int* __restrict__ dst,
                          const float* __restrict__ norm, const float* __restrict__ Z,
                          float* __restrict__ agg) {
    constexpr int LPE = OUTC / 4;       // lanes per edge
    int gid = blockIdx.x * 256 + threadIdx.x;
    int e = gid / LPE;
    int l = gid % LPE;
    if (e >= NE) return;
    int s = src[e], d = dst[e];
    float nm = norm[e];
    float4 v = *reinterpret_cast<const float4*>(Z + (size_t)s * OUTC + l * 4);
    float* a = agg + (size_t)d * OUTC + l * 4;
    atomicAdd(a + 0, v.x * nm);
    atomicAdd(a + 1, v.y * nm);
    atomicAdd(a + 2, v.z * nm);
    atomicAdd(a + 3, v.w * nm);
}

// ---------------- pointwise ----------------
__global__ void k_sigmoid(float* __restrict__ ru, const float* __restrict__ b1) {
    int i = blockIdx.x * 256 + threadIdx.x;        // over NN*128
    if (i < NN * 128) {
        int j = i & 127;
        float v = ru[i] + b1[j];
        ru[i] = 1.f / (1.f + expf(-v));
    }
}

__global__ void k_final(const float* __restrict__ agg2, const float* __restrict__ ru,
                        const float* __restrict__ Hm, const float* __restrict__ b2,
                        float* __restrict__ out) {
    int i = blockIdx.x * 256 + threadIdx.x;        // over NN*64
    if (i < NN * 64) {
        int row = i >> 6, j = i & 63;
        float u = ru[row * 128 + 64 + j];
        float c = tanhf(agg2[i] + b2[j]);
        out[i] = u * Hm[i] + (1.f - u) * c;
    }
}

extern "C" void kernel_launch(void* const* d_in, const int* in_sizes, int n_in,
                              void* d_out, int out_size, void* d_ws, size_t ws_size,
                              hipStream_t stream) {
    const float* X  = (const float*)d_in[0];
    const float* Hm = (const float*)d_in[1];
    const int*   ei = (const int*)d_in[2];           // [2][E]
    const float* w  = (const float*)d_in[3];
    const float* W1 = (const float*)d_in[4];         // [128][128]
    const float* b1 = (const float*)d_in[5];
    const float* W2 = (const float*)d_in[6];         // [128][64]
    const float* b2 = (const float*)d_in[7];
    float* out = (float*)d_out;

    const int* src = ei;
    const int* dst = ei + NE;

    float* ws   = (float*)d_ws;
    float* dinv = ws;                        // NN
    float* norm = dinv + NN;                 // NE
    float* Z1   = norm + NE;                 // NN*128
    float* agg1 = Z1 + NN * 128;             // NN*128  (becomes RU in place)
    float* Z2   = agg1 + NN * 128;           // NN*64
    float* agg2 = Z2 + NN * 64;              // NN*64

    const int BN  = (NN + 255) / 256;
    const int BE  = (NE + 255) / 256;

    // deg / dinv / norm
    k_deg_init<<<BN, 256, 0, stream>>>(dinv);
    k_deg_acc<<<BE, 256, 0, stream>>>(dst, w, dinv);
    k_dinv<<<BN, 256, 0, stream>>>(dinv);
    k_norm<<<BE, 256, 0, stream>>>(src, dst, w, dinv, norm);

    // conv1: Z1 = [X|H] @ W1 ; agg1 = S @ Z1 ; ru = sigmoid(agg1 + b1)
    const int GB = (NN + 31) / 32;
    k_gemm<128, 0><<<GB, 256, 0, stream>>>(X, Hm, nullptr, W1, Z1);
    k_self<128><<<(NN * 32 + 255) / 256, 256, 0, stream>>>(Z1, dinv, agg1);
    k_scatter<128><<<(NE * 32 + 255) / 256, 256, 0, stream>>>(src, dst, norm, Z1, agg1);
    k_sigmoid<<<(NN * 128 + 255) / 256, 256, 0, stream>>>(agg1, b1);

    // conv2: Z2 = [X|H*r] @ W2 ; agg2 = S @ Z2 ; out = u*H + (1-u)*tanh(agg2+b2)
    k_gemm<64, 1><<<GB, 256, 0, stream>>>(X, Hm, agg1, W2, Z2);
    k_self<64><<<(NN * 16 + 255) / 256, 256, 0, stream>>>(Z2, dinv, agg2);
    k_scatter<64><<<(NE * 16 + 255) / 256, 256, 0, stream>>>(src, dst, norm, Z2, agg2);
    k_final<<<(NN * 64 + 255) / 256, 256, 0, stream>>>(agg2, agg1, Hm, b2, out);
}

// Round 2
// 437.891 us; speedup vs baseline: 4.9814x; 4.9814x over previous
//
#include <hip/hip_runtime.h>
#include <hip/hip_bf16.h>

#define NN 50000
#define NE 800000
// IN = OUT = 64, fan_in = 128

// ---------------- init: deg=1 (self loop), cnt=0 ----------------
__global__ void k_init(float* __restrict__ deg, int* __restrict__ cnt) {
    int i = blockIdx.x * 256 + threadIdx.x;
    if (i < NN) { deg[i] = 1.0f; cnt[i] = 0; }
}

// ---------------- per-edge: accumulate weighted degree + dst counts ----------------
__global__ void k_prep(const int* __restrict__ dst, const float* __restrict__ w,
                       float* __restrict__ deg, int* __restrict__ cnt) {
    int e = blockIdx.x * 256 + threadIdx.x;
    if (e < NE) {
        int d = dst[e];
        atomicAdd(&deg[d], w[e]);
        atomicAdd(&cnt[d], 1);
    }
}

__global__ void k_dinv(float* __restrict__ deg) {
    int i = blockIdx.x * 256 + threadIdx.x;
    if (i < NN) {
        float d = deg[i];
        deg[i] = (d > 0.f) ? rsqrtf(fmaxf(d, 1e-12f)) : 0.f;
    }
}

// ---------------- single-block exclusive scan over cnt -> start (+cursor copy) ----------------
__global__ void k_scan(const int* __restrict__ cnt, int* __restrict__ start,
                       int* __restrict__ cursor) {
    __shared__ int lds[1024];
    __shared__ int carryS;
    int tid = threadIdx.x;
    if (tid == 0) carryS = 0;
    __syncthreads();
    for (int base = 0; base < NN; base += 1024) {
        int idx = base + tid;
        int v = (idx < NN) ? cnt[idx] : 0;
        lds[tid] = v;
        __syncthreads();
        #pragma unroll
        for (int off = 1; off < 1024; off <<= 1) {
            int t = (tid >= off) ? lds[tid - off] : 0;
            __syncthreads();
            lds[tid] += t;
            __syncthreads();
        }
        int excl = lds[tid] - v;
        int carry = carryS;
        if (idx < NN) {
            start[idx] = carry + excl;
            cursor[idx] = carry + excl;
        }
        __syncthreads();
        if (tid == 1023) carryS += lds[1023];
        __syncthreads();
    }
    if (tid == 0) start[NN] = carryS;
}

// ---------------- CSR fill: position atomics + fused norm compute ----------------
__global__ void k_fill(const int* __restrict__ src, const int* __restrict__ dst,
                       const float* __restrict__ w, const float* __restrict__ dinv,
                       int* __restrict__ cursor, int* __restrict__ srcP,
                       float* __restrict__ normP) {
    int e = blockIdx.x * 256 + threadIdx.x;
    if (e < NE) {
        int s = src[e], d = dst[e];
        int pos = atomicAdd(&cursor[d], 1);
        srcP[pos] = s;
        normP[pos] = dinv[s] * w[e] * dinv[d];
    }
}

// ---------------- GEMM: out[N][OUTC] = concat(X, H or H*r) @ W ----------------
// MODE 0: in = [X | H]     MODE 1: in = [X | H * RU[:, :64]]
template <int OUTC, int MODE>
__launch_bounds__(256)
__global__ void k_gemm(const float* __restrict__ X, const float* __restrict__ Hm,
                       const float* __restrict__ RU, const float* __restrict__ W,
                       float* __restrict__ out) {
    constexpr int ROWS = 32;
    __shared__ float wLds[128 * OUTC];
    __shared__ float inLds[ROWS][128];
    const int tid = threadIdx.x;

    for (int i = tid; i < 128 * OUTC; i += 256) wLds[i] = W[i];

    const int row0 = blockIdx.x * ROWS;
    for (int i = tid; i < ROWS * 128; i += 256) {
        int rr = i >> 7, k = i & 127;
        int row = row0 + rr;
        float v = 0.f;
        if (row < NN) {
            if (k < 64) {
                v = X[row * 64 + k];
            } else {
                float h = Hm[row * 64 + (k - 64)];
                if (MODE == 1) h *= RU[row * 128 + (k - 64)];
                v = h;
            }
        }
        inLds[rr][k] = v;
    }
    __syncthreads();

    constexpr int CG = OUTC / 4;        // float4 column groups
    constexpr int RSTEP = 256 / CG;
    const int cg = tid % CG;
    const int rsub = tid / CG;
    const float4* w4 = reinterpret_cast<const float4*>(wLds) + cg;

    for (int rr = rsub; rr < ROWS; rr += RSTEP) {
        int row = row0 + rr;
        if (row >= NN) continue;
        float4 acc = {0.f, 0.f, 0.f, 0.f};
        #pragma unroll 16
        for (int k = 0; k < 128; ++k) {
            float v = inLds[rr][k];
            float4 wv = w4[k * CG];
            acc.x += v * wv.x; acc.y += v * wv.y;
            acc.z += v * wv.z; acc.w += v * wv.w;
        }
        *reinterpret_cast<float4*>(out + (size_t)row * OUTC + cg * 4) = acc;
    }
}

// ---------------- CSR gather + fused epilogue ----------------
// MODE 0 (conv1): out = sigmoid(agg + b)          [NN x 128]
// MODE 1 (conv2): out = u*H + (1-u)*tanh(agg + b) [NN x 64], u = RU[:,64:]
template <int OUTC, int MODE>
__launch_bounds__(256)
__global__ void k_gather(const int* __restrict__ start, const int* __restrict__ srcP,
                         const float* __restrict__ normP, const float* __restrict__ Z,
                         const float* __restrict__ dinv, const float* __restrict__ bias,
                         const float* __restrict__ RU, const float* __restrict__ Hm,
                         float* __restrict__ out) {
    constexpr int GRP = OUTC / 4;                 // lanes per node
    constexpr int NPB = 256 / GRP;                // nodes per block
    const int node = blockIdx.x * NPB + threadIdx.x / GRP;
    const int l = threadIdx.x % GRP;
    if (node >= NN) return;

    const int e0 = start[node], e1 = start[node + 1];

    // self loop: dinv[node]^2 * Z[node]
    float dn = dinv[node];
    dn = dn * dn;
    float4 acc = *reinterpret_cast<const float4*>(Z + (size_t)node * OUTC + l * 4);
    acc.x *= dn; acc.y *= dn; acc.z *= dn; acc.w *= dn;

    for (int e = e0; e < e1; ++e) {
        int s = srcP[e];
        float nm = normP[e];
        float4 z = *reinterpret_cast<const float4*>(Z + (size_t)s * OUTC + l * 4);
        acc.x += z.x * nm; acc.y += z.y * nm;
        acc.z += z.z * nm; acc.w += z.w * nm;
    }

    const int c = l * 4;
    float4 bb = *reinterpret_cast<const float4*>(bias + c);
    acc.x += bb.x; acc.y += bb.y; acc.z += bb.z; acc.w += bb.w;

    if (MODE == 0) {
        float4 o;
        o.x = 1.f / (1.f + expf(-acc.x));
        o.y = 1.f / (1.f + expf(-acc.y));
        o.z = 1.f / (1.f + expf(-acc.z));
        o.w = 1.f / (1.f + expf(-acc.w));
        *reinterpret_cast<float4*>(out + (size_t)node * 128 + c) = o;
    } else {
        float4 u4 = *reinterpret_cast<const float4*>(RU + (size_t)node * 128 + 64 + c);
        float4 h4 = *reinterpret_cast<const float4*>(Hm + (size_t)node * 64 + c);
        float4 o;
        o.x = u4.x * h4.x + (1.f - u4.x) * tanhf(acc.x);
        o.y = u4.y * h4.y + (1.f - u4.y) * tanhf(acc.y);
        o.z = u4.z * h4.z + (1.f - u4.z) * tanhf(acc.z);
        o.w = u4.w * h4.w + (1.f - u4.w) * tanhf(acc.w);
        *reinterpret_cast<float4*>(out + (size_t)node * 64 + c) = o;
    }
}

extern "C" void kernel_launch(void* const* d_in, const int* in_sizes, int n_in,
                              void* d_out, int out_size, void* d_ws, size_t ws_size,
                              hipStream_t stream) {
    const float* X  = (const float*)d_in[0];
    const float* Hm = (const float*)d_in[1];
    const int*   ei = (const int*)d_in[2];           // [2][E]
    const float* w  = (const float*)d_in[3];
    const float* W1 = (const float*)d_in[4];         // [128][128]
    const float* b1 = (const float*)d_in[5];
    const float* W2 = (const float*)d_in[6];         // [128][64]
    const float* b2 = (const float*)d_in[7];
    float* out = (float*)d_out;

    const int* src = ei;
    const int* dst = ei + NE;

    char* p = (char*)d_ws;
    float* dinv   = (float*)p;  p += sizeof(float) * NN;
    int*   cnt    = (int*)p;    p += sizeof(int) * NN;
    int*   start  = (int*)p;    p += sizeof(int) * (NN + 1);
    int*   cursor = (int*)p;    p += sizeof(int) * (NN + 64);   // pad
    int*   srcP   = (int*)p;    p += sizeof(int) * NE;
    float* normP  = (float*)p;  p += sizeof(float) * NE;
    float* Z1     = (float*)p;  p += sizeof(float) * NN * 128;
    float* RU     = (float*)p;  p += sizeof(float) * NN * 128;
    float* Z2     = (float*)p;  p += sizeof(float) * NN * 64;

    const int BN = (NN + 255) / 256;
    const int BE = (NE + 255) / 256;
    const int GB = (NN + 31) / 32;

    // CSR build + norms
    k_init<<<BN, 256, 0, stream>>>(dinv, cnt);
    k_prep<<<BE, 256, 0, stream>>>(dst, w, dinv, cnt);
    k_dinv<<<BN, 256, 0, stream>>>(dinv);
    k_scan<<<1, 1024, 0, stream>>>(cnt, start, cursor);
    k_fill<<<BE, 256, 0, stream>>>(src, dst, w, dinv, cursor, srcP, normP);

    // conv1: Z1 = [X|H] @ W1 ; RU = sigmoid(S@Z1 + b1)
    k_gemm<128, 0><<<GB, 256, 0, stream>>>(X, Hm, nullptr, W1, Z1);
    k_gather<128, 0><<<(NN * 32 + 255) / 256, 256, 0, stream>>>(
        start, srcP, normP, Z1, dinv, b1, nullptr, nullptr, RU);

    // conv2: Z2 = [X|H*r] @ W2 ; out = u*H + (1-u)*tanh(S@Z2 + b2)
    k_gemm<64, 1><<<GB, 256, 0, stream>>>(X, Hm, RU, W2, Z2);
    k_gather<64, 1><<<(NN * 16 + 255) / 256, 256, 0, stream>>>(
        start, srcP, normP, Z2, dinv, b2, RU, Hm, out);
}

// Round 3
// 336.388 us; speedup vs baseline: 6.4846x; 1.3017x over previous
//
#include <hip/hip_runtime.h>
#include <hip/hip_bf16.h>

#define NN 50000
#define NE 800000
// IN = OUT = 64, fan_in = 128
#define SCAN_B ((NN + 255) / 256)   // 196 scan blocks

// ---------------- init: deg=1 (self loop), cnt=0 ----------------
__global__ void k_init(float* __restrict__ deg, int* __restrict__ cnt) {
    int i = blockIdx.x * 256 + threadIdx.x;
    if (i < NN) { deg[i] = 1.0f; cnt[i] = 0; }
}

// ---------------- per-edge: accumulate weighted degree + dst counts ----------------
__global__ void k_prep(const int* __restrict__ dst, const float* __restrict__ w,
                       float* __restrict__ deg, int* __restrict__ cnt) {
    int e = blockIdx.x * 256 + threadIdx.x;
    if (e < NE) {
        int d = dst[e];
        atomicAdd(&deg[d], w[e]);
        atomicAdd(&cnt[d], 1);
    }
}

// ---------------- scan step 1: per-256-chunk exclusive scan (+ fused dinv) ----------------
__global__ void k_scan1(const int* __restrict__ cnt, int* __restrict__ start,
                        int* __restrict__ blockSums, float* __restrict__ deg) {
    __shared__ int lds[256];
    const int tid = threadIdx.x;
    const int idx = blockIdx.x * 256 + tid;
    int v = (idx < NN) ? cnt[idx] : 0;
    lds[tid] = v;
    __syncthreads();
    #pragma unroll
    for (int off = 1; off < 256; off <<= 1) {
        int t = (tid >= off) ? lds[tid - off] : 0;
        __syncthreads();
        lds[tid] += t;
        __syncthreads();
    }
    if (idx < NN) {
        start[idx] = lds[tid] - v;          // chunk-local exclusive
        float d = deg[idx];
        deg[idx] = (d > 0.f) ? rsqrtf(fmaxf(d, 1e-12f)) : 0.f;
    }
    if (tid == 255) blockSums[blockIdx.x] = lds[255];
}

// ---------------- scan step 2: exclusive scan of block sums (196 values) ----------------
__global__ void k_scan2(int* __restrict__ blockSums, int* __restrict__ blockOffs,
                        int* __restrict__ start) {
    __shared__ int lds[256];
    const int tid = threadIdx.x;
    int v = (tid < SCAN_B) ? blockSums[tid] : 0;
    lds[tid] = v;
    __syncthreads();
    #pragma unroll
    for (int off = 1; off < 256; off <<= 1) {
        int t = (tid >= off) ? lds[tid - off] : 0;
        __syncthreads();
        lds[tid] += t;
        __syncthreads();
    }
    if (tid < SCAN_B) blockOffs[tid] = lds[tid] - v;
    if (tid == 0) start[NN] = NE;           // total count is static
}

// ---------------- scan step 3: add block offset, mirror to cursor ----------------
__global__ void k_scan3(int* __restrict__ start, const int* __restrict__ blockOffs,
                        int* __restrict__ cursor) {
    const int idx = blockIdx.x * 256 + threadIdx.x;
    if (idx < NN) {
        int s = start[idx] + blockOffs[blockIdx.x];
        start[idx] = s;
        cursor[idx] = s;
    }
}

// ---------------- CSR fill: position atomics + fused norm compute ----------------
__global__ void k_fill(const int* __restrict__ src, const int* __restrict__ dst,
                       const float* __restrict__ w, const float* __restrict__ dinv,
                       int* __restrict__ cursor, int* __restrict__ srcP,
                       float* __restrict__ normP) {
    int e = blockIdx.x * 256 + threadIdx.x;
    if (e < NE) {
        int s = src[e], d = dst[e];
        int pos = atomicAdd(&cursor[d], 1);
        srcP[pos] = s;
        normP[pos] = dinv[s] * w[e] * dinv[d];
    }
}

// ---------------- GEMM: out[N][OUTC] = concat(X, H or H*r) @ W ----------------
// MODE 0: in = [X | H]     MODE 1: in = [X | H * RU[:, :64]]
template <int OUTC, int MODE>
__launch_bounds__(256)
__global__ void k_gemm(const float* __restrict__ X, const float* __restrict__ Hm,
                       const float* __restrict__ RU, const float* __restrict__ W,
                       float* __restrict__ out) {
    constexpr int ROWS = 32;
    __shared__ float wLds[128 * OUTC];
    __shared__ float inLds[ROWS][128];
    const int tid = threadIdx.x;

    for (int i = tid; i < 128 * OUTC; i += 256) wLds[i] = W[i];

    const int row0 = blockIdx.x * ROWS;
    for (int i = tid; i < ROWS * 128; i += 256) {
        int rr = i >> 7, k = i & 127;
        int row = row0 + rr;
        float v = 0.f;
        if (row < NN) {
            if (k < 64) {
                v = X[row * 64 + k];
            } else {
                float h = Hm[row * 64 + (k - 64)];
                if (MODE == 1) h *= RU[row * 128 + (k - 64)];
                v = h;
            }
        }
        inLds[rr][k] = v;
    }
    __syncthreads();

    constexpr int CG = OUTC / 4;        // float4 column groups
    constexpr int RSTEP = 256 / CG;
    const int cg = tid % CG;
    const int rsub = tid / CG;
    const float4* w4 = reinterpret_cast<const float4*>(wLds) + cg;

    for (int rr = rsub; rr < ROWS; rr += RSTEP) {
        int row = row0 + rr;
        if (row >= NN) continue;
        float4 acc = {0.f, 0.f, 0.f, 0.f};
        #pragma unroll 16
        for (int k = 0; k < 128; ++k) {
            float v = inLds[rr][k];
            float4 wv = w4[k * CG];
            acc.x += v * wv.x; acc.y += v * wv.y;
            acc.z += v * wv.z; acc.w += v * wv.w;
        }
        *reinterpret_cast<float4*>(out + (size_t)row * OUTC + cg * 4) = acc;
    }
}

// ---------------- CSR gather + fused epilogue ----------------
// MODE 0 (conv1): out = sigmoid(agg + b)          [NN x 128]
// MODE 1 (conv2): out = u*H + (1-u)*tanh(agg + b) [NN x 64], u = RU[:,64:]
template <int OUTC, int MODE>
__launch_bounds__(256)
__global__ void k_gather(const int* __restrict__ start, const int* __restrict__ srcP,
                         const float* __restrict__ normP, const float* __restrict__ Z,
                         const float* __restrict__ dinv, const float* __restrict__ bias,
                         const float* __restrict__ RU, const float* __restrict__ Hm,
                         float* __restrict__ out) {
    constexpr int GRP = OUTC / 4;                 // lanes per node
    constexpr int NPB = 256 / GRP;                // nodes per block
    const int node = blockIdx.x * NPB + threadIdx.x / GRP;
    const int l = threadIdx.x % GRP;
    if (node >= NN) return;

    const int e0 = start[node], e1 = start[node + 1];

    // self loop: dinv[node]^2 * Z[node]
    float dn = dinv[node];
    dn = dn * dn;
    float4 acc = *reinterpret_cast<const float4*>(Z + (size_t)node * OUTC + l * 4);
    acc.x *= dn; acc.y *= dn; acc.z *= dn; acc.w *= dn;

    for (int e = e0; e < e1; ++e) {
        int s = srcP[e];
        float nm = normP[e];
        float4 z = *reinterpret_cast<const float4*>(Z + (size_t)s * OUTC + l * 4);
        acc.x += z.x * nm; acc.y += z.y * nm;
        acc.z += z.z * nm; acc.w += z.w * nm;
    }

    const int c = l * 4;
    float4 bb = *reinterpret_cast<const float4*>(bias + c);
    acc.x += bb.x; acc.y += bb.y; acc.z += bb.z; acc.w += bb.w;

    if (MODE == 0) {
        float4 o;
        o.x = 1.f / (1.f + expf(-acc.x));
        o.y = 1.f / (1.f + expf(-acc.y));
        o.z = 1.f / (1.f + expf(-acc.z));
        o.w = 1.f / (1.f + expf(-acc.w));
        *reinterpret_cast<float4*>(out + (size_t)node * 128 + c) = o;
    } else {
        float4 u4 = *reinterpret_cast<const float4*>(RU + (size_t)node * 128 + 64 + c);
        float4 h4 = *reinterpret_cast<const float4*>(Hm + (size_t)node * 64 + c);
        float4 o;
        o.x = u4.x * h4.x + (1.f - u4.x) * tanhf(acc.x);
        o.y = u4.y * h4.y + (1.f - u4.y) * tanhf(acc.y);
        o.z = u4.z * h4.z + (1.f - u4.z) * tanhf(acc.z);
        o.w = u4.w * h4.w + (1.f - u4.w) * tanhf(acc.w);
        *reinterpret_cast<float4*>(out + (size_t)node * 64 + c) = o;
    }
}

extern "C" void kernel_launch(void* const* d_in, const int* in_sizes, int n_in,
                              void* d_out, int out_size, void* d_ws, size_t ws_size,
                              hipStream_t stream) {
    const float* X  = (const float*)d_in[0];
    const float* Hm = (const float*)d_in[1];
    const int*   ei = (const int*)d_in[2];           // [2][E]
    const float* w  = (const float*)d_in[3];
    const float* W1 = (const float*)d_in[4];         // [128][128]
    const float* b1 = (const float*)d_in[5];
    const float* W2 = (const float*)d_in[6];         // [128][64]
    const float* b2 = (const float*)d_in[7];
    float* out = (float*)d_out;

    const int* src = ei;
    const int* dst = ei + NE;

    char* p = (char*)d_ws;
    float* dinv      = (float*)p;  p += sizeof(float) * NN;
    int*   cnt       = (int*)p;    p += sizeof(int) * NN;
    int*   start     = (int*)p;    p += sizeof(int) * (NN + 1);
    int*   cursor    = (int*)p;    p += sizeof(int) * (NN + 63);
    int*   blockSums = (int*)p;    p += sizeof(int) * 256;
    int*   blockOffs = (int*)p;    p += sizeof(int) * 256;
    int*   srcP      = (int*)p;    p += sizeof(int) * NE;
    float* normP     = (float*)p;  p += sizeof(float) * NE;
    float* Z1        = (float*)p;  p += sizeof(float) * NN * 128;
    float* RU        = (float*)p;  p += sizeof(float) * NN * 128;
    float* Z2        = (float*)p;  p += sizeof(float) * NN * 64;

    const int BN = (NN + 255) / 256;
    const int BE = (NE + 255) / 256;
    const int GB = (NN + 31) / 32;

    // CSR build + norms
    k_init<<<BN, 256, 0, stream>>>(dinv, cnt);
    k_prep<<<BE, 256, 0, stream>>>(dst, w, dinv, cnt);
    k_scan1<<<SCAN_B, 256, 0, stream>>>(cnt, start, blockSums, dinv);
    k_scan2<<<1, 256, 0, stream>>>(blockSums, blockOffs, start);
    k_scan3<<<SCAN_B, 256, 0, stream>>>(start, blockOffs, cursor);
    k_fill<<<BE, 256, 0, stream>>>(src, dst, w, dinv, cursor, srcP, normP);

    // conv1: Z1 = [X|H] @ W1 ; RU = sigmoid(S@Z1 + b1)
    k_gemm<128, 0><<<GB, 256, 0, stream>>>(X, Hm, nullptr, W1, Z1);
    k_gather<128, 0><<<(NN * 32 + 255) / 256, 256, 0, stream>>>(
        start, srcP, normP, Z1, dinv, b1, nullptr, nullptr, RU);

    // conv2: Z2 = [X|H*r] @ W2 ; out = u*H + (1-u)*tanh(S@Z2 + b2)
    k_gemm<64, 1><<<GB, 256, 0, stream>>>(X, Hm, RU, W2, Z2);
    k_gather<64, 1><<<(NN * 16 + 255) / 256, 256, 0, stream>>>(
        start, srcP, normP, Z2, dinv, b2, RU, Hm, out);
}

// Round 4
// 233.983 us; speedup vs baseline: 9.3226x; 1.4377x over previous
//
#include <hip/hip_runtime.h>
#include <hip/hip_bf16.h>

#define NN 50000
#define NE 800000
// IN = OUT = 64, fan_in = 128
#define SCAN_B ((NN + 255) / 256)   // 196 scan blocks
#define PACK_SHIFT 44
#define PACK_MASK ((1ULL << PACK_SHIFT) - 1)

// ---------------- per-edge: one packed atomic = position + weighted degree ----------------
__global__ void k_prep(const int* __restrict__ dst, const float* __restrict__ w,
                       unsigned long long* __restrict__ packed, int* __restrict__ edgePos) {
    int e = blockIdx.x * 256 + threadIdx.x;
    if (e < NE) {
        unsigned long long inc =
            (1ULL << PACK_SHIFT) | (unsigned long long)(w[e] * 4294967296.0f);
        unsigned long long old = atomicAdd(&packed[dst[e]], inc);
        edgePos[e] = (int)(old >> PACK_SHIFT);
    }
}

// ---------------- scan step 1: extract cnt + dinv from packed, chunk-local scan ----------------
__global__ void k_scan1(const unsigned long long* __restrict__ packed,
                        int* __restrict__ start, int* __restrict__ blockSums,
                        float* __restrict__ dinv) {
    __shared__ int lds[256];
    const int tid = threadIdx.x;
    const int idx = blockIdx.x * 256 + tid;
    int v = 0;
    if (idx < NN) {
        unsigned long long p = packed[idx];
        v = (int)(p >> PACK_SHIFT);
        float sumw = (float)((double)(p & PACK_MASK) * (1.0 / 4294967296.0));
        dinv[idx] = rsqrtf(1.0f + sumw);     // deg >= 1 (self loop)
    }
    lds[tid] = v;
    __syncthreads();
    #pragma unroll
    for (int off = 1; off < 256; off <<= 1) {
        int t = (tid >= off) ? lds[tid - off] : 0;
        __syncthreads();
        lds[tid] += t;
        __syncthreads();
    }
    if (idx < NN) start[idx] = lds[tid] - v;   // chunk-local exclusive
    if (tid == 255) blockSums[blockIdx.x] = lds[255];
}

// ---------------- scan step 2: exclusive scan of block sums ----------------
__global__ void k_scan2(int* __restrict__ blockSums, int* __restrict__ blockOffs,
                        int* __restrict__ start) {
    __shared__ int lds[256];
    const int tid = threadIdx.x;
    int v = (tid < SCAN_B) ? blockSums[tid] : 0;
    lds[tid] = v;
    __syncthreads();
    #pragma unroll
    for (int off = 1; off < 256; off <<= 1) {
        int t = (tid >= off) ? lds[tid - off] : 0;
        __syncthreads();
        lds[tid] += t;
        __syncthreads();
    }
    if (tid < SCAN_B) blockOffs[tid] = lds[tid] - v;
    if (tid == 0) start[NN] = NE;
}

// ---------------- scan step 3: add block offset ----------------
__global__ void k_scan3(int* __restrict__ start, const int* __restrict__ blockOffs) {
    const int idx = blockIdx.x * 256 + threadIdx.x;
    if (idx < NN) start[idx] += blockOffs[blockIdx.x];
}

// ---------------- CSR fill: atomic-free (position known), fused norm ----------------
__global__ void k_fill(const int* __restrict__ src, const int* __restrict__ dst,
                       const float* __restrict__ w, const float* __restrict__ dinv,
                       const int* __restrict__ start, const int* __restrict__ edgePos,
                       int* __restrict__ srcP, float* __restrict__ normP) {
    int e = blockIdx.x * 256 + threadIdx.x;
    if (e < NE) {
        int s = src[e], d = dst[e];
        int pos = start[d] + edgePos[e];
        srcP[pos] = s;
        normP[pos] = dinv[s] * w[e] * dinv[d];
    }
}

// ---------------- GEMM: out[N][OUTC] = concat(X, H or H*r) @ W ----------------
// K chunked by 32 (24KB LDS), 64 rows/block, per-thread reg accumulators,
// W micro-chunk (8 k) held in registers, float4 LDS reads both sides.
// MODE 0: in = [X | H]     MODE 1: in = [X | H * RU[:, :64]]
template <int OUTC, int MODE>
__launch_bounds__(256)
__global__ void k_gemm(const float* __restrict__ X, const float* __restrict__ Hm,
                       const float* __restrict__ RU, const float* __restrict__ W,
                       float* __restrict__ out) {
    constexpr int ROWS = 64;
    constexpr int CG = OUTC / 4;          // float4 col groups: 32 or 16
    constexpr int RSTEP = 256 / CG;       // 8 or 16
    constexpr int RPT = ROWS / RSTEP;     // 8 or 4

    __shared__ float wS[32 * OUTC];       // k-slice of W
    __shared__ float inS[ROWS * 32];      // k-slice of input rows

    const int tid = threadIdx.x;
    const int cg = tid % CG;
    const int rsub = tid / CG;
    const int row0 = blockIdx.x * ROWS;

    float4 acc[RPT];
    #pragma unroll
    for (int r = 0; r < RPT; ++r) acc[r] = {0.f, 0.f, 0.f, 0.f};

    float4* wS4 = reinterpret_cast<float4*>(wS);
    float4* inS4 = reinterpret_cast<float4*>(inS);

    for (int kc = 0; kc < 4; ++kc) {
        // stage W slice: rows kc*32 .. kc*32+31 (contiguous)
        const float4* Wg = reinterpret_cast<const float4*>(W + kc * 32 * OUTC);
        #pragma unroll
        for (int i = tid; i < 32 * CG; i += 256) wS4[i] = Wg[i];
        // stage input slice: 64 rows x 32 k
        #pragma unroll
        for (int i = tid; i < ROWS * 8; i += 256) {
            int rr = i >> 3, j = i & 7;
            int row = row0 + rr;
            float4 v = {0.f, 0.f, 0.f, 0.f};
            if (row < NN) {
                if (kc < 2) {
                    v = reinterpret_cast<const float4*>(X)[row * 16 + kc * 8 + j];
                } else {
                    v = reinterpret_cast<const float4*>(Hm)[row * 16 + (kc - 2) * 8 + j];
                    if (MODE == 1) {
                        float4 rv = reinterpret_cast<const float4*>(RU)[row * 32 + (kc - 2) * 8 + j];
                        v.x *= rv.x; v.y *= rv.y; v.z *= rv.z; v.w *= rv.w;
                    }
                }
            }
            inS4[rr * 8 + j] = v;
        }
        __syncthreads();

        #pragma unroll
        for (int k8 = 0; k8 < 4; ++k8) {
            float4 wr[8];
            #pragma unroll
            for (int j = 0; j < 8; ++j) wr[j] = wS4[(k8 * 8 + j) * CG + cg];
            #pragma unroll
            for (int r = 0; r < RPT; ++r) {
                const int rr = rsub + r * RSTEP;
                float4 a0 = inS4[rr * 8 + k8 * 2];
                float4 a1 = inS4[rr * 8 + k8 * 2 + 1];
                acc[r].x += a0.x * wr[0].x; acc[r].y += a0.x * wr[0].y;
                acc[r].z += a0.x * wr[0].z; acc[r].w += a0.x * wr[0].w;
                acc[r].x += a0.y * wr[1].x; acc[r].y += a0.y * wr[1].y;
                acc[r].z += a0.y * wr[1].z; acc[r].w += a0.y * wr[1].w;
                acc[r].x += a0.z * wr[2].x; acc[r].y += a0.z * wr[2].y;
                acc[r].z += a0.z * wr[2].z; acc[r].w += a0.z * wr[2].w;
                acc[r].x += a0.w * wr[3].x; acc[r].y += a0.w * wr[3].y;
                acc[r].z += a0.w * wr[3].z; acc[r].w += a0.w * wr[3].w;
                acc[r].x += a1.x * wr[4].x; acc[r].y += a1.x * wr[4].y;
                acc[r].z += a1.x * wr[4].z; acc[r].w += a1.x * wr[4].w;
                acc[r].x += a1.y * wr[5].x; acc[r].y += a1.y * wr[5].y;
                acc[r].z += a1.y * wr[5].z; acc[r].w += a1.y * wr[5].w;
                acc[r].x += a1.z * wr[6].x; acc[r].y += a1.z * wr[6].y;
                acc[r].z += a1.z * wr[6].z; acc[r].w += a1.z * wr[6].w;
                acc[r].x += a1.w * wr[7].x; acc[r].y += a1.w * wr[7].y;
                acc[r].z += a1.w * wr[7].z; acc[r].w += a1.w * wr[7].w;
            }
        }
        __syncthreads();
    }

    #pragma unroll
    for (int r = 0; r < RPT; ++r) {
        int row = row0 + rsub + r * RSTEP;
        if (row < NN)
            reinterpret_cast<float4*>(out)[(size_t)row * CG + cg] = acc[r];
    }
}

// ---------------- CSR gather + fused epilogue ----------------
// MODE 0 (conv1): out = sigmoid(agg + b)          [NN x 128]
// MODE 1 (conv2): out = u*H + (1-u)*tanh(agg + b) [NN x 64], u = RU[:,64:]
template <int OUTC, int MODE>
__launch_bounds__(256)
__global__ void k_gather(const int* __restrict__ start, const int* __restrict__ srcP,
                         const float* __restrict__ normP, const float* __restrict__ Z,
                         const float* __restrict__ dinv, const float* __restrict__ bias,
                         const float* __restrict__ RU, const float* __restrict__ Hm,
                         float* __restrict__ out) {
    constexpr int GRP = OUTC / 4;                 // lanes per node
    constexpr int NPB = 256 / GRP;                // nodes per block
    const int node = blockIdx.x * NPB + threadIdx.x / GRP;
    const int l = threadIdx.x % GRP;
    if (node >= NN) return;

    const int e0 = start[node], e1 = start[node + 1];

    float dn = dinv[node];
    dn = dn * dn;
    float4 acc = *reinterpret_cast<const float4*>(Z + (size_t)node * OUTC + l * 4);
    acc.x *= dn; acc.y *= dn; acc.z *= dn; acc.w *= dn;

    for (int e = e0; e < e1; ++e) {
        int s = srcP[e];
        float nm = normP[e];
        float4 z = *reinterpret_cast<const float4*>(Z + (size_t)s * OUTC + l * 4);
        acc.x += z.x * nm; acc.y += z.y * nm;
        acc.z += z.z * nm; acc.w += z.w * nm;
    }

    const int c = l * 4;
    float4 bb = *reinterpret_cast<const float4*>(bias + c);
    acc.x += bb.x; acc.y += bb.y; acc.z += bb.z; acc.w += bb.w;

    if (MODE == 0) {
        float4 o;
        o.x = 1.f / (1.f + expf(-acc.x));
        o.y = 1.f / (1.f + expf(-acc.y));
        o.z = 1.f / (1.f + expf(-acc.z));
        o.w = 1.f / (1.f + expf(-acc.w));
        *reinterpret_cast<float4*>(out + (size_t)node * 128 + c) = o;
    } else {
        float4 u4 = *reinterpret_cast<const float4*>(RU + (size_t)node * 128 + 64 + c);
        float4 h4 = *reinterpret_cast<const float4*>(Hm + (size_t)node * 64 + c);
        float4 o;
        o.x = u4.x * h4.x + (1.f - u4.x) * tanhf(acc.x);
        o.y = u4.y * h4.y + (1.f - u4.y) * tanhf(acc.y);
        o.z = u4.z * h4.z + (1.f - u4.z) * tanhf(acc.z);
        o.w = u4.w * h4.w + (1.f - u4.w) * tanhf(acc.w);
        *reinterpret_cast<float4*>(out + (size_t)node * 64 + c) = o;
    }
}

extern "C" void kernel_launch(void* const* d_in, const int* in_sizes, int n_in,
                              void* d_out, int out_size, void* d_ws, size_t ws_size,
                              hipStream_t stream) {
    const float* X  = (const float*)d_in[0];
    const float* Hm = (const float*)d_in[1];
    const int*   ei = (const int*)d_in[2];           // [2][E]
    const float* w  = (const float*)d_in[3];
    const float* W1 = (const float*)d_in[4];         // [128][128]
    const float* b1 = (const float*)d_in[5];
    const float* W2 = (const float*)d_in[6];         // [128][64]
    const float* b2 = (const float*)d_in[7];
    float* out = (float*)d_out;

    const int* src = ei;
    const int* dst = ei + NE;

    char* p = (char*)d_ws;
    unsigned long long* packed = (unsigned long long*)p; p += sizeof(unsigned long long) * NN;
    float* dinv      = (float*)p;  p += sizeof(float) * NN;
    int*   start     = (int*)p;    p += sizeof(int) * (NN + 1);
    int*   blockSums = (int*)p;    p += sizeof(int) * 256;
    int*   blockOffs = (int*)p;    p += sizeof(int) * 255;   // keep 8B alignment downstream
    int*   edgePos   = (int*)p;    p += sizeof(int) * NE;
    int*   srcP      = (int*)p;    p += sizeof(int) * NE;
    float* normP     = (float*)p;  p += sizeof(float) * NE;
    float* Z1        = (float*)p;  p += sizeof(float) * NN * 128;
    float* RU        = (float*)p;  p += sizeof(float) * NN * 128;
    float* Z2        = (float*)p;  p += sizeof(float) * NN * 64;

    const int BE = (NE + 255) / 256;
    const int GB = (NN + 63) / 64;

    // CSR build
    hipMemsetAsync(packed, 0, sizeof(unsigned long long) * NN, stream);
    k_prep<<<BE, 256, 0, stream>>>(dst, w, packed, edgePos);
    k_scan1<<<SCAN_B, 256, 0, stream>>>(packed, start, blockSums, dinv);
    k_scan2<<<1, 256, 0, stream>>>(blockSums, blockOffs, start);
    k_scan3<<<SCAN_B, 256, 0, stream>>>(start, blockOffs);
    k_fill<<<BE, 256, 0, stream>>>(src, dst, w, dinv, start, edgePos, srcP, normP);

    // conv1: Z1 = [X|H] @ W1 ; RU = sigmoid(S@Z1 + b1)
    k_gemm<128, 0><<<GB, 256, 0, stream>>>(X, Hm, nullptr, W1, Z1);
    k_gather<128, 0><<<(NN * 32 + 255) / 256, 256, 0, stream>>>(
        start, srcP, normP, Z1, dinv, b1, nullptr, nullptr, RU);

    // conv2: Z2 = [X|H*r] @ W2 ; out = u*H + (1-u)*tanh(S@Z2 + b2)
    k_gemm<64, 1><<<GB, 256, 0, stream>>>(X, Hm, RU, W2, Z2);
    k_gather<64, 1><<<(NN * 16 + 255) / 256, 256, 0, stream>>>(
        start, srcP, normP, Z2, dinv, b2, RU, Hm, out);
}

// Round 5
// 212.972 us; speedup vs baseline: 10.2423x; 1.0987x over previous
//
#include <hip/hip_runtime.h>
#include <hip/hip_bf16.h>
#include <hip/hip_fp16.h>

#define NN 50000
#define NE 800000
// IN = OUT = 64, fan_in = 128
#define SCAN_B ((NN + 255) / 256)   // 196 scan blocks
#define PACK_SHIFT 44
#define PACK_MASK ((1ULL << PACK_SHIFT) - 1)

__device__ __forceinline__ unsigned int f2bf(float x) {
    unsigned int u = __float_as_uint(x);
    return (u + 0x7FFFu + ((u >> 16) & 1u)) >> 16;
}
__device__ __forceinline__ float bf2f(unsigned int b) {
    return __uint_as_float(b << 16);
}

// ---------------- per-edge: one packed atomic = position + weighted degree ----------------
__global__ void k_prep(const int* __restrict__ dst, const float* __restrict__ w,
                       unsigned long long* __restrict__ packed, int* __restrict__ edgePos) {
    int e = blockIdx.x * 256 + threadIdx.x;
    if (e < NE) {
        unsigned long long inc =
            (1ULL << PACK_SHIFT) | (unsigned long long)(w[e] * 4294967296.0f);
        unsigned long long old = atomicAdd(&packed[dst[e]], inc);
        edgePos[e] = (int)(old >> PACK_SHIFT);
    }
}

// ---------------- scan step 1: extract cnt + dinv from packed, chunk-local scan ----------------
__global__ void k_scan1(const unsigned long long* __restrict__ packed,
                        int* __restrict__ start, int* __restrict__ blockSums,
                        float* __restrict__ dinv) {
    __shared__ int lds[256];
    const int tid = threadIdx.x;
    const int idx = blockIdx.x * 256 + tid;
    int v = 0;
    if (idx < NN) {
        unsigned long long p = packed[idx];
        v = (int)(p >> PACK_SHIFT);
        float sumw = (float)((double)(p & PACK_MASK) * (1.0 / 4294967296.0));
        dinv[idx] = rsqrtf(1.0f + sumw);     // deg >= 1 (self loop)
    }
    lds[tid] = v;
    __syncthreads();
    #pragma unroll
    for (int off = 1; off < 256; off <<= 1) {
        int t = (tid >= off) ? lds[tid - off] : 0;
        __syncthreads();
        lds[tid] += t;
        __syncthreads();
    }
    if (idx < NN) start[idx] = lds[tid] - v;   // chunk-local exclusive
    if (tid == 255) blockSums[blockIdx.x] = lds[255];
}

// ---------------- scan step 2: exclusive scan of block sums ----------------
__global__ void k_scan2(int* __restrict__ blockSums, int* __restrict__ blockOffs,
                        int* __restrict__ start) {
    __shared__ int lds[256];
    const int tid = threadIdx.x;
    int v = (tid < SCAN_B) ? blockSums[tid] : 0;
    lds[tid] = v;
    __syncthreads();
    #pragma unroll
    for (int off = 1; off < 256; off <<= 1) {
        int t = (tid >= off) ? lds[tid - off] : 0;
        __syncthreads();
        lds[tid] += t;
        __syncthreads();
    }
    if (tid < SCAN_B) blockOffs[tid] = lds[tid] - v;
    if (tid == 0) start[NN] = NE;
}

// ---------------- scan step 3: add block offset ----------------
__global__ void k_scan3(int* __restrict__ start, const int* __restrict__ blockOffs) {
    const int idx = blockIdx.x * 256 + threadIdx.x;
    if (idx < NN) start[idx] += blockOffs[blockIdx.x];
}

// ---------------- CSR fill: atomic-free, packed (src | fp16 norm) ----------------
__global__ void k_fill(const int* __restrict__ src, const int* __restrict__ dst,
                       const float* __restrict__ w, const float* __restrict__ dinv,
                       const int* __restrict__ start, const int* __restrict__ edgePos,
                       unsigned int* __restrict__ snP) {
    int e = blockIdx.x * 256 + threadIdx.x;
    if (e < NE) {
        int s = src[e], d = dst[e];
        int pos = start[d] + edgePos[e];
        float nm = dinv[s] * w[e] * dinv[d];
        unsigned int hn = __half_as_ushort(__float2half(nm));
        snP[pos] = (unsigned int)s | (hn << 16);
    }
}

// ---------------- GEMM: outB[N][OUTC](bf16) = concat(X, H or H*r) @ W ----------------
// MODE 0: in = [X | H]     MODE 1: in = [X | H * RU[:, :64]]
template <int OUTC, int MODE>
__launch_bounds__(256)
__global__ void k_gemm(const float* __restrict__ X, const float* __restrict__ Hm,
                       const float* __restrict__ RU, const float* __restrict__ W,
                       uint2* __restrict__ outB) {
    constexpr int ROWS = 64;
    constexpr int CG = OUTC / 4;          // float4 col groups: 32 or 16
    constexpr int RSTEP = 256 / CG;       // 8 or 16
    constexpr int RPT = ROWS / RSTEP;     // 8 or 4

    __shared__ float wS[32 * OUTC];       // k-slice of W
    __shared__ float inS[ROWS * 32];      // k-slice of input rows

    const int tid = threadIdx.x;
    const int cg = tid % CG;
    const int rsub = tid / CG;
    const int row0 = blockIdx.x * ROWS;

    float4 acc[RPT];
    #pragma unroll
    for (int r = 0; r < RPT; ++r) acc[r] = {0.f, 0.f, 0.f, 0.f};

    float4* wS4 = reinterpret_cast<float4*>(wS);
    float4* inS4 = reinterpret_cast<float4*>(inS);

    for (int kc = 0; kc < 4; ++kc) {
        const float4* Wg = reinterpret_cast<const float4*>(W + kc * 32 * OUTC);
        #pragma unroll
        for (int i = tid; i < 32 * CG; i += 256) wS4[i] = Wg[i];
        #pragma unroll
        for (int i = tid; i < ROWS * 8; i += 256) {
            int rr = i >> 3, j = i & 7;
            int row = row0 + rr;
            float4 v = {0.f, 0.f, 0.f, 0.f};
            if (row < NN) {
                if (kc < 2) {
                    v = reinterpret_cast<const float4*>(X)[row * 16 + kc * 8 + j];
                } else {
                    v = reinterpret_cast<const float4*>(Hm)[row * 16 + (kc - 2) * 8 + j];
                    if (MODE == 1) {
                        float4 rv = reinterpret_cast<const float4*>(RU)[row * 32 + (kc - 2) * 8 + j];
                        v.x *= rv.x; v.y *= rv.y; v.z *= rv.z; v.w *= rv.w;
                    }
                }
            }
            inS4[rr * 8 + j] = v;
        }
        __syncthreads();

        #pragma unroll
        for (int k8 = 0; k8 < 4; ++k8) {
            float4 wr[8];
            #pragma unroll
            for (int j = 0; j < 8; ++j) wr[j] = wS4[(k8 * 8 + j) * CG + cg];
            #pragma unroll
            for (int r = 0; r < RPT; ++r) {
                const int rr = rsub + r * RSTEP;
                float4 a0 = inS4[rr * 8 + k8 * 2];
                float4 a1 = inS4[rr * 8 + k8 * 2 + 1];
                acc[r].x += a0.x * wr[0].x; acc[r].y += a0.x * wr[0].y;
                acc[r].z += a0.x * wr[0].z; acc[r].w += a0.x * wr[0].w;
                acc[r].x += a0.y * wr[1].x; acc[r].y += a0.y * wr[1].y;
                acc[r].z += a0.y * wr[1].z; acc[r].w += a0.y * wr[1].w;
                acc[r].x += a0.z * wr[2].x; acc[r].y += a0.z * wr[2].y;
                acc[r].z += a0.z * wr[2].z; acc[r].w += a0.z * wr[2].w;
                acc[r].x += a0.w * wr[3].x; acc[r].y += a0.w * wr[3].y;
                acc[r].z += a0.w * wr[3].z; acc[r].w += a0.w * wr[3].w;
                acc[r].x += a1.x * wr[4].x; acc[r].y += a1.x * wr[4].y;
                acc[r].z += a1.x * wr[4].z; acc[r].w += a1.x * wr[4].w;
                acc[r].x += a1.y * wr[5].x; acc[r].y += a1.y * wr[5].y;
                acc[r].z += a1.y * wr[5].z; acc[r].w += a1.y * wr[5].w;
                acc[r].x += a1.z * wr[6].x; acc[r].y += a1.z * wr[6].y;
                acc[r].z += a1.z * wr[6].z; acc[r].w += a1.z * wr[6].w;
                acc[r].x += a1.w * wr[7].x; acc[r].y += a1.w * wr[7].y;
                acc[r].z += a1.w * wr[7].z; acc[r].w += a1.w * wr[7].w;
            }
        }
        __syncthreads();
    }

    #pragma unroll
    for (int r = 0; r < RPT; ++r) {
        int row = row0 + rsub + r * RSTEP;
        if (row < NN) {
            uint2 o;
            o.x = f2bf(acc[r].x) | (f2bf(acc[r].y) << 16);
            o.y = f2bf(acc[r].z) | (f2bf(acc[r].w) << 16);
            outB[(size_t)row * CG + cg] = o;
        }
    }
}

// ---------------- CSR gather (bf16 Z, packed src|norm) + fused epilogue ----------------
// MODE 0 (conv1): out = sigmoid(agg + b)          [NN x 128] f32
// MODE 1 (conv2): out = u*H + (1-u)*tanh(agg + b) [NN x 64]  f32, u = RU[:,64:]
template <int OUTC, int MODE>
__launch_bounds__(256)
__global__ void k_gather(const int* __restrict__ start, const unsigned int* __restrict__ snP,
                         const uint2* __restrict__ Zb, const float* __restrict__ dinv,
                         const float* __restrict__ bias, const float* __restrict__ RU,
                         const float* __restrict__ Hm, float* __restrict__ out) {
    constexpr int GRP = OUTC / 4;                 // lanes per node (uint2 = 4 bf16 each)
    constexpr int NPB = 256 / GRP;                // nodes per block
    const int node = blockIdx.x * NPB + threadIdx.x / GRP;
    const int l = threadIdx.x % GRP;
    if (node >= NN) return;

    const int e0 = start[node], e1 = start[node + 1];

    float dn = dinv[node];
    dn = dn * dn;
    uint2 zs = Zb[(size_t)node * GRP + l];
    float4 acc;
    acc.x = bf2f(zs.x & 0xFFFFu) * dn;
    acc.y = bf2f(zs.x >> 16) * dn;
    acc.z = bf2f(zs.y & 0xFFFFu) * dn;
    acc.w = bf2f(zs.y >> 16) * dn;

    for (int e = e0; e < e1; ++e) {
        unsigned int sn = snP[e];
        int s = (int)(sn & 0xFFFFu);
        float nm = __half2float(__ushort_as_half((unsigned short)(sn >> 16)));
        uint2 z = Zb[(size_t)s * GRP + l];
        acc.x += bf2f(z.x & 0xFFFFu) * nm;
        acc.y += bf2f(z.x >> 16) * nm;
        acc.z += bf2f(z.y & 0xFFFFu) * nm;
        acc.w += bf2f(z.y >> 16) * nm;
    }

    const int c = l * 4;
    float4 bb = *reinterpret_cast<const float4*>(bias + c);
    acc.x += bb.x; acc.y += bb.y; acc.z += bb.z; acc.w += bb.w;

    if (MODE == 0) {
        float4 o;
        o.x = 1.f / (1.f + expf(-acc.x));
        o.y = 1.f / (1.f + expf(-acc.y));
        o.z = 1.f / (1.f + expf(-acc.z));
        o.w = 1.f / (1.f + expf(-acc.w));
        *reinterpret_cast<float4*>(out + (size_t)node * 128 + c) = o;
    } else {
        float4 u4 = *reinterpret_cast<const float4*>(RU + (size_t)node * 128 + 64 + c);
        float4 h4 = *reinterpret_cast<const float4*>(Hm + (size_t)node * 64 + c);
        float4 o;
        o.x = u4.x * h4.x + (1.f - u4.x) * tanhf(acc.x);
        o.y = u4.y * h4.y + (1.f - u4.y) * tanhf(acc.y);
        o.z = u4.z * h4.z + (1.f - u4.z) * tanhf(acc.z);
        o.w = u4.w * h4.w + (1.f - u4.w) * tanhf(acc.w);
        *reinterpret_cast<float4*>(out + (size_t)node * 64 + c) = o;
    }
}

extern "C" void kernel_launch(void* const* d_in, const int* in_sizes, int n_in,
                              void* d_out, int out_size, void* d_ws, size_t ws_size,
                              hipStream_t stream) {
    const float* X  = (const float*)d_in[0];
    const float* Hm = (const float*)d_in[1];
    const int*   ei = (const int*)d_in[2];           // [2][E]
    const float* w  = (const float*)d_in[3];
    const float* W1 = (const float*)d_in[4];         // [128][128]
    const float* b1 = (const float*)d_in[5];
    const float* W2 = (const float*)d_in[6];         // [128][64]
    const float* b2 = (const float*)d_in[7];
    float* out = (float*)d_out;

    const int* src = ei;
    const int* dst = ei + NE;

    char* p = (char*)d_ws;
    unsigned long long* packed = (unsigned long long*)p; p += sizeof(unsigned long long) * NN;
    float* dinv      = (float*)p;  p += sizeof(float) * NN;
    int*   start     = (int*)p;    p += sizeof(int) * (NN + 1);
    int*   blockSums = (int*)p;    p += sizeof(int) * 256;
    int*   blockOffs = (int*)p;    p += sizeof(int) * 255;
    int*   edgePos   = (int*)p;    p += sizeof(int) * NE;
    unsigned int* snP = (unsigned int*)p; p += sizeof(unsigned int) * NE;
    uint2* Z1b       = (uint2*)p;  p += sizeof(uint2) * NN * 32;   // NN x 128 bf16
    uint2* Z2b       = (uint2*)p;  p += sizeof(uint2) * NN * 16;   // NN x 64 bf16
    float* RU        = (float*)p;  p += sizeof(float) * NN * 128;

    const int BE = (NE + 255) / 256;
    const int GB = (NN + 63) / 64;

    // CSR build
    hipMemsetAsync(packed, 0, sizeof(unsigned long long) * NN, stream);
    k_prep<<<BE, 256, 0, stream>>>(dst, w, packed, edgePos);
    k_scan1<<<SCAN_B, 256, 0, stream>>>(packed, start, blockSums, dinv);
    k_scan2<<<1, 256, 0, stream>>>(blockSums, blockOffs, start);
    k_scan3<<<SCAN_B, 256, 0, stream>>>(start, blockOffs);
    k_fill<<<BE, 256, 0, stream>>>(src, dst, w, dinv, start, edgePos, snP);

    // conv1: Z1 = [X|H] @ W1 ; RU = sigmoid(S@Z1 + b1)
    k_gemm<128, 0><<<GB, 256, 0, stream>>>(X, Hm, nullptr, W1, Z1b);
    k_gather<128, 0><<<(NN * 32 + 255) / 256, 256, 0, stream>>>(
        start, snP, Z1b, dinv, b1, nullptr, nullptr, RU);

    // conv2: Z2 = [X|H*r] @ W2 ; out = u*H + (1-u)*tanh(S@Z2 + b2)
    k_gemm<64, 1><<<GB, 256, 0, stream>>>(X, Hm, RU, W2, Z2b);
    k_gather<64, 1><<<(NN * 16 + 255) / 256, 256, 0, stream>>>(
        start, snP, Z2b, dinv, b2, RU, Hm, out);
}

// Round 6
// 172.214 us; speedup vs baseline: 12.6664x; 1.2367x over previous
//
#include <hip/hip_runtime.h>
#include <hip/hip_bf16.h>
#include <hip/hip_fp16.h>

#define NN 50000
#define NE 800000
// IN = OUT = 64, fan_in = 128
#define SCAN_B ((NN + 255) / 256)   // 196 scan blocks
#define PREP_B ((NE + 255) / 256)   // 3125 prep blocks
#define GEMM_B ((NN + 63) / 64)     // 782 gemm blocks
#define PACK_SHIFT 44
#define PACK_MASK ((1ULL << PACK_SHIFT) - 1)

__device__ __forceinline__ unsigned int f2bf(float x) {
    unsigned int u = __float_as_uint(x);
    return (u + 0x7FFFu + ((u >> 16) & 1u)) >> 16;
}
__device__ __forceinline__ float bf2f(unsigned int b) {
    return __uint_as_float(b << 16);
}

// ---------------- GEMM body (shared by fused and standalone kernels) ----------------
// MODE 0: in = [X | H]     MODE 1: in = [X | H * RU[:, :64]]
template <int OUTC, int MODE>
__device__ __forceinline__ void gemm_body(const float* __restrict__ X,
                                          const float* __restrict__ Hm,
                                          const float* __restrict__ RU,
                                          const float* __restrict__ W,
                                          uint2* __restrict__ outB, int bid,
                                          float* wS, float* inS) {
    constexpr int ROWS = 64;
    constexpr int CG = OUTC / 4;          // float4 col groups: 32 or 16
    constexpr int RSTEP = 256 / CG;       // 8 or 16
    constexpr int RPT = ROWS / RSTEP;     // 8 or 4

    const int tid = threadIdx.x;
    const int cg = tid % CG;
    const int rsub = tid / CG;
    const int row0 = bid * ROWS;

    float4 acc[RPT];
    #pragma unroll
    for (int r = 0; r < RPT; ++r) acc[r] = {0.f, 0.f, 0.f, 0.f};

    float4* wS4 = reinterpret_cast<float4*>(wS);
    float4* inS4 = reinterpret_cast<float4*>(inS);

    for (int kc = 0; kc < 4; ++kc) {
        const float4* Wg = reinterpret_cast<const float4*>(W + kc * 32 * OUTC);
        #pragma unroll
        for (int i = tid; i < 32 * CG; i += 256) wS4[i] = Wg[i];
        #pragma unroll
        for (int i = tid; i < ROWS * 8; i += 256) {
            int rr = i >> 3, j = i & 7;
            int row = row0 + rr;
            float4 v = {0.f, 0.f, 0.f, 0.f};
            if (row < NN) {
                if (kc < 2) {
                    v = reinterpret_cast<const float4*>(X)[row * 16 + kc * 8 + j];
                } else {
                    v = reinterpret_cast<const float4*>(Hm)[row * 16 + (kc - 2) * 8 + j];
                    if (MODE == 1) {
                        float4 rv = reinterpret_cast<const float4*>(RU)[row * 32 + (kc - 2) * 8 + j];
                        v.x *= rv.x; v.y *= rv.y; v.z *= rv.z; v.w *= rv.w;
                    }
                }
            }
            inS4[rr * 8 + j] = v;
        }
        __syncthreads();

        #pragma unroll
        for (int k8 = 0; k8 < 4; ++k8) {
            float4 wr[8];
            #pragma unroll
            for (int j = 0; j < 8; ++j) wr[j] = wS4[(k8 * 8 + j) * CG + cg];
            #pragma unroll
            for (int r = 0; r < RPT; ++r) {
                const int rr = rsub + r * RSTEP;
                float4 a0 = inS4[rr * 8 + k8 * 2];
                float4 a1 = inS4[rr * 8 + k8 * 2 + 1];
                acc[r].x += a0.x * wr[0].x; acc[r].y += a0.x * wr[0].y;
                acc[r].z += a0.x * wr[0].z; acc[r].w += a0.x * wr[0].w;
                acc[r].x += a0.y * wr[1].x; acc[r].y += a0.y * wr[1].y;
                acc[r].z += a0.y * wr[1].z; acc[r].w += a0.y * wr[1].w;
                acc[r].x += a0.z * wr[2].x; acc[r].y += a0.z * wr[2].y;
                acc[r].z += a0.z * wr[2].z; acc[r].w += a0.z * wr[2].w;
                acc[r].x += a0.w * wr[3].x; acc[r].y += a0.w * wr[3].y;
                acc[r].z += a0.w * wr[3].z; acc[r].w += a0.w * wr[3].w;
                acc[r].x += a1.x * wr[4].x; acc[r].y += a1.x * wr[4].y;
                acc[r].z += a1.x * wr[4].z; acc[r].w += a1.x * wr[4].w;
                acc[r].x += a1.y * wr[5].x; acc[r].y += a1.y * wr[5].y;
                acc[r].z += a1.y * wr[5].z; acc[r].w += a1.y * wr[5].w;
                acc[r].x += a1.z * wr[6].x; acc[r].y += a1.z * wr[6].y;
                acc[r].z += a1.z * wr[6].z; acc[r].w += a1.z * wr[6].w;
                acc[r].x += a1.w * wr[7].x; acc[r].y += a1.w * wr[7].y;
                acc[r].z += a1.w * wr[7].z; acc[r].w += a1.w * wr[7].w;
            }
        }
        __syncthreads();
    }

    #pragma unroll
    for (int r = 0; r < RPT; ++r) {
        int row = row0 + rsub + r * RSTEP;
        if (row < NN) {
            uint2 o;
            o.x = f2bf(acc[r].x) | (f2bf(acc[r].y) << 16);
            o.y = f2bf(acc[r].z) | (f2bf(acc[r].w) << 16);
            outB[(size_t)row * CG + cg] = o;
        }
    }
}

// ---------------- fused: prep (latency-bound atomics) || gemm1 (compute) ----------------
__launch_bounds__(256)
__global__ void k_gemm1_prep(const float* __restrict__ X, const float* __restrict__ Hm,
                             const float* __restrict__ W,
                             uint2* __restrict__ outB,
                             const int* __restrict__ dst, const float* __restrict__ w,
                             unsigned long long* __restrict__ packed,
                             int* __restrict__ edgePos) {
    __shared__ float wS[32 * 128];
    __shared__ float inS[64 * 32];
    if (blockIdx.x < PREP_B) {
        int e = blockIdx.x * 256 + threadIdx.x;
        if (e < NE) {
            unsigned long long inc =
                (1ULL << PACK_SHIFT) | (unsigned long long)(w[e] * 4294967296.0f);
            unsigned long long old = atomicAdd(&packed[dst[e]], inc);
            edgePos[e] = (int)(old >> PACK_SHIFT);
        }
        return;
    }
    gemm_body<128, 0>(X, Hm, nullptr, W, outB, blockIdx.x - PREP_B, wS, inS);
}

// ---------------- standalone gemm2 ----------------
__launch_bounds__(256)
__global__ void k_gemm2(const float* __restrict__ X, const float* __restrict__ Hm,
                        const float* __restrict__ RU, const float* __restrict__ W,
                        uint2* __restrict__ outB) {
    __shared__ float wS[32 * 64];
    __shared__ float inS[64 * 32];
    gemm_body<64, 1>(X, Hm, RU, W, outB, blockIdx.x, wS, inS);
}

// ---------------- scan step 1: extract cnt + dinv from packed, chunk-local scan ----------------
__global__ void k_scan1(const unsigned long long* __restrict__ packed,
                        int* __restrict__ start, int* __restrict__ blockSums,
                        float* __restrict__ dinv) {
    __shared__ int lds[256];
    const int tid = threadIdx.x;
    const int idx = blockIdx.x * 256 + tid;
    int v = 0;
    if (idx < NN) {
        unsigned long long p = packed[idx];
        v = (int)(p >> PACK_SHIFT);
        float sumw = (float)((double)(p & PACK_MASK) * (1.0 / 4294967296.0));
        dinv[idx] = rsqrtf(1.0f + sumw);     // deg >= 1 (self loop)
    }
    lds[tid] = v;
    __syncthreads();
    #pragma unroll
    for (int off = 1; off < 256; off <<= 1) {
        int t = (tid >= off) ? lds[tid - off] : 0;
        __syncthreads();
        lds[tid] += t;
        __syncthreads();
    }
    if (idx < NN) start[idx] = lds[tid] - v;   // chunk-local exclusive
    if (tid == 255) blockSums[blockIdx.x] = lds[255];
}

// ---------------- scan step 2 ----------------
__global__ void k_scan2(int* __restrict__ blockSums, int* __restrict__ blockOffs,
                        int* __restrict__ start) {
    __shared__ int lds[256];
    const int tid = threadIdx.x;
    int v = (tid < SCAN_B) ? blockSums[tid] : 0;
    lds[tid] = v;
    __syncthreads();
    #pragma unroll
    for (int off = 1; off < 256; off <<= 1) {
        int t = (tid >= off) ? lds[tid - off] : 0;
        __syncthreads();
        lds[tid] += t;
        __syncthreads();
    }
    if (tid < SCAN_B) blockOffs[tid] = lds[tid] - v;
    if (tid == 0) start[NN] = NE;
}

// ---------------- scan step 3 ----------------
__global__ void k_scan3(int* __restrict__ start, const int* __restrict__ blockOffs) {
    const int idx = blockIdx.x * 256 + threadIdx.x;
    if (idx < NN) start[idx] += blockOffs[blockIdx.x];
}

// ---------------- CSR fill: atomic-free, packed (src | fp16 norm) ----------------
__global__ void k_fill(const int* __restrict__ src, const int* __restrict__ dst,
                       const float* __restrict__ w, const float* __restrict__ dinv,
                       const int* __restrict__ start, const int* __restrict__ edgePos,
                       unsigned int* __restrict__ snP) {
    int e = blockIdx.x * 256 + threadIdx.x;
    if (e < NE) {
        int s = src[e], d = dst[e];
        int pos = start[d] + edgePos[e];
        float nm = dinv[s] * w[e] * dinv[d];
        unsigned int hn = __half_as_ushort(__float2half(nm));
        snP[pos] = (unsigned int)s | (hn << 16);
    }
}

// ---------------- CSR gather, 8x unrolled for MLP + fused epilogue ----------------
// MODE 0 (conv1): out = sigmoid(agg + b)          [NN x 128] f32
// MODE 1 (conv2): out = u*H + (1-u)*tanh(agg + b) [NN x 64]  f32, u = RU[:,64:]
template <int OUTC, int MODE>
__launch_bounds__(256)
__global__ void k_gather(const int* __restrict__ start, const unsigned int* __restrict__ snP,
                         const uint2* __restrict__ Zb, const float* __restrict__ dinv,
                         const float* __restrict__ bias, const float* __restrict__ RU,
                         const float* __restrict__ Hm, float* __restrict__ out) {
    constexpr int GRP = OUTC / 4;                 // lanes per node (uint2 = 4 bf16 each)
    constexpr int NPB = 256 / GRP;                // nodes per block
    const int node = blockIdx.x * NPB + threadIdx.x / GRP;
    const int l = threadIdx.x % GRP;
    if (node >= NN) return;

    const int e0 = start[node], e1 = start[node + 1];

    float dn = dinv[node];
    dn = dn * dn;
    uint2 zs = Zb[(size_t)node * GRP + l];
    float4 acc;
    acc.x = bf2f(zs.x & 0xFFFFu) * dn;
    acc.y = bf2f(zs.x >> 16) * dn;
    acc.z = bf2f(zs.y & 0xFFFFu) * dn;
    acc.w = bf2f(zs.y >> 16) * dn;

    #define EFMA(Z, NM) \
        acc.x += bf2f((Z).x & 0xFFFFu) * (NM); \
        acc.y += bf2f((Z).x >> 16) * (NM);     \
        acc.z += bf2f((Z).y & 0xFFFFu) * (NM); \
        acc.w += bf2f((Z).y >> 16) * (NM);

    int e = e0;
    for (; e + 8 <= e1; e += 8) {
        unsigned sn0 = snP[e],     sn1 = snP[e + 1], sn2 = snP[e + 2], sn3 = snP[e + 3];
        unsigned sn4 = snP[e + 4], sn5 = snP[e + 5], sn6 = snP[e + 6], sn7 = snP[e + 7];
        uint2 z0 = Zb[(size_t)(sn0 & 0xFFFFu) * GRP + l];
        uint2 z1 = Zb[(size_t)(sn1 & 0xFFFFu) * GRP + l];
        uint2 z2 = Zb[(size_t)(sn2 & 0xFFFFu) * GRP + l];
        uint2 z3 = Zb[(size_t)(sn3 & 0xFFFFu) * GRP + l];
        uint2 z4 = Zb[(size_t)(sn4 & 0xFFFFu) * GRP + l];
        uint2 z5 = Zb[(size_t)(sn5 & 0xFFFFu) * GRP + l];
        uint2 z6 = Zb[(size_t)(sn6 & 0xFFFFu) * GRP + l];
        uint2 z7 = Zb[(size_t)(sn7 & 0xFFFFu) * GRP + l];
        float n0 = __half2float(__ushort_as_half((unsigned short)(sn0 >> 16)));
        float n1 = __half2float(__ushort_as_half((unsigned short)(sn1 >> 16)));
        float n2 = __half2float(__ushort_as_half((unsigned short)(sn2 >> 16)));
        float n3 = __half2float(__ushort_as_half((unsigned short)(sn3 >> 16)));
        float n4 = __half2float(__ushort_as_half((unsigned short)(sn4 >> 16)));
        float n5 = __half2float(__ushort_as_half((unsigned short)(sn5 >> 16)));
        float n6 = __half2float(__ushort_as_half((unsigned short)(sn6 >> 16)));
        float n7 = __half2float(__ushort_as_half((unsigned short)(sn7 >> 16)));
        EFMA(z0, n0) EFMA(z1, n1) EFMA(z2, n2) EFMA(z3, n3)
        EFMA(z4, n4) EFMA(z5, n5) EFMA(z6, n6) EFMA(z7, n7)
    }
    if (e + 4 <= e1) {
        unsigned sn0 = snP[e], sn1 = snP[e + 1], sn2 = snP[e + 2], sn3 = snP[e + 3];
        uint2 z0 = Zb[(size_t)(sn0 & 0xFFFFu) * GRP + l];
        uint2 z1 = Zb[(size_t)(sn1 & 0xFFFFu) * GRP + l];
        uint2 z2 = Zb[(size_t)(sn2 & 0xFFFFu) * GRP + l];
        uint2 z3 = Zb[(size_t)(sn3 & 0xFFFFu) * GRP + l];
        float n0 = __half2float(__ushort_as_half((unsigned short)(sn0 >> 16)));
        float n1 = __half2float(__ushort_as_half((unsigned short)(sn1 >> 16)));
        float n2 = __half2float(__ushort_as_half((unsigned short)(sn2 >> 16)));
        float n3 = __half2float(__ushort_as_half((unsigned short)(sn3 >> 16)));
        EFMA(z0, n0) EFMA(z1, n1) EFMA(z2, n2) EFMA(z3, n3)
        e += 4;
    }
    for (; e < e1; ++e) {
        unsigned sn = snP[e];
        float nm = __half2float(__ushort_as_half((unsigned short)(sn >> 16)));
        uint2 z = Zb[(size_t)(sn & 0xFFFFu) * GRP + l];
        EFMA(z, nm)
    }
    #undef EFMA

    const int c = l * 4;
    float4 bb = *reinterpret_cast<const float4*>(bias + c);
    acc.x += bb.x; acc.y += bb.y; acc.z += bb.z; acc.w += bb.w;

    if (MODE == 0) {
        float4 o;
        o.x = 1.f / (1.f + expf(-acc.x));
        o.y = 1.f / (1.f + expf(-acc.y));
        o.z = 1.f / (1.f + expf(-acc.z));
        o.w = 1.f / (1.f + expf(-acc.w));
        *reinterpret_cast<float4*>(out + (size_t)node * 128 + c) = o;
    } else {
        float4 u4 = *reinterpret_cast<const float4*>(RU + (size_t)node * 128 + 64 + c);
        float4 h4 = *reinterpret_cast<const float4*>(Hm + (size_t)node * 64 + c);
        float4 o;
        o.x = u4.x * h4.x + (1.f - u4.x) * tanhf(acc.x);
        o.y = u4.y * h4.y + (1.f - u4.y) * tanhf(acc.y);
        o.z = u4.z * h4.z + (1.f - u4.z) * tanhf(acc.z);
        o.w = u4.w * h4.w + (1.f - u4.w) * tanhf(acc.w);
        *reinterpret_cast<float4*>(out + (size_t)node * 64 + c) = o;
    }
}

extern "C" void kernel_launch(void* const* d_in, const int* in_sizes, int n_in,
                              void* d_out, int out_size, void* d_ws, size_t ws_size,
                              hipStream_t stream) {
    const float* X  = (const float*)d_in[0];
    const float* Hm = (const float*)d_in[1];
    const int*   ei = (const int*)d_in[2];           // [2][E]
    const float* w  = (const float*)d_in[3];
    const float* W1 = (const float*)d_in[4];         // [128][128]
    const float* b1 = (const float*)d_in[5];
    const float* W2 = (const float*)d_in[6];         // [128][64]
    const float* b2 = (const float*)d_in[7];
    float* out = (float*)d_out;

    const int* src = ei;
    const int* dst = ei + NE;

    char* p = (char*)d_ws;
    unsigned long long* packed = (unsigned long long*)p; p += sizeof(unsigned long long) * NN;
    float* dinv      = (float*)p;  p += sizeof(float) * NN;
    int*   start     = (int*)p;    p += sizeof(int) * (NN + 1);
    int*   blockSums = (int*)p;    p += sizeof(int) * 256;
    int*   blockOffs = (int*)p;    p += sizeof(int) * 255;
    int*   edgePos   = (int*)p;    p += sizeof(int) * NE;
    unsigned int* snP = (unsigned int*)p; p += sizeof(unsigned int) * NE;
    uint2* Z1b       = (uint2*)p;  p += sizeof(uint2) * NN * 32;   // NN x 128 bf16
    uint2* Z2b       = (uint2*)p;  p += sizeof(uint2) * NN * 16;   // NN x 64 bf16
    float* RU        = (float*)p;  p += sizeof(float) * NN * 128;

    const int BE = PREP_B;

    // fused: CSR prep atomics (latency) || gemm1 (compute)
    hipMemsetAsync(packed, 0, sizeof(unsigned long long) * NN, stream);
    k_gemm1_prep<<<PREP_B + GEMM_B, 256, 0, stream>>>(X, Hm, W1, Z1b, dst, w, packed, edgePos);

    // CSR finalize
    k_scan1<<<SCAN_B, 256, 0, stream>>>(packed, start, blockSums, dinv);
    k_scan2<<<1, 256, 0, stream>>>(blockSums, blockOffs, start);
    k_scan3<<<SCAN_B, 256, 0, stream>>>(start, blockOffs);
    k_fill<<<BE, 256, 0, stream>>>(src, dst, w, dinv, start, edgePos, snP);

    // conv1 aggregate: RU = sigmoid(S@Z1 + b1)
    k_gather<128, 0><<<(NN * 32 + 255) / 256, 256, 0, stream>>>(
        start, snP, Z1b, dinv, b1, nullptr, nullptr, RU);

    // conv2: Z2 = [X|H*r] @ W2 ; out = u*H + (1-u)*tanh(S@Z2 + b2)
    k_gemm2<<<GEMM_B, 256, 0, stream>>>(X, Hm, RU, W2, Z2b);
    k_gather<64, 1><<<(NN * 16 + 255) / 256, 256, 0, stream>>>(
        start, snP, Z2b, dinv, b2, RU, Hm, out);
}

// Round 7
// 166.197 us; speedup vs baseline: 13.1250x; 1.0362x over previous
//
#include <hip/hip_runtime.h>
#include <hip/hip_bf16.h>
#include <hip/hip_fp16.h>

#define NN 50000
#define NE 800000
// IN = OUT = 64, fan_in = 128
#define SCAN_B ((NN + 255) / 256)       // 196
#define PB ((NE + 1023) / 1024)         // 782 prep/fill blocks (4 edges/thread)
#define GB ((NN + 63) / 64)             // 782 gemm blocks
#define PACK_SHIFT 44
#define PACK_MASK ((1ULL << PACK_SHIFT) - 1)

__device__ __forceinline__ unsigned int f2bf(float x) {
    unsigned int u = __float_as_uint(x);
    return (u + 0x7FFFu + ((u >> 16) & 1u)) >> 16;
}
__device__ __forceinline__ float bf2f(unsigned int b) {
    return __uint_as_float(b << 16);
}

// ---------------- generic GEMM core: 64 rows/block, k-slice 16 ----------------
// SRC 0: in=[X|H], NKC=8   SRC 1: in=X (W rows 0..63), NKC=4
// SRC 2: in=H*r (r from RUb bf16; W pre-offset to rows 64..127), NKC=4
// OMODE 0: outB bf16      OMODE 1: outF f32      OMODE 2: outB bf16 of (acc + addF)
template <int OUTC, int NKC, int SRC, int OMODE>
__device__ __forceinline__ void gemm_core(
    const float* __restrict__ X, const float* __restrict__ Hm,
    const unsigned int* __restrict__ RUb, const float* __restrict__ W,
    const float* __restrict__ addF, uint2* __restrict__ outB,
    float* __restrict__ outF, int bid, float4* wS4, float4* inS4)
{
    constexpr int CG = OUTC / 4;          // 32 or 16
    constexpr int RSTEP = 256 / CG;       // 8 or 16
    constexpr int RPT = 64 / RSTEP;       // 8 or 4
    const int tid = threadIdx.x;
    const int cg = tid % CG;
    const int rsub = tid / CG;
    const int row0 = bid * 64;

    float4 acc[RPT];
    #pragma unroll
    for (int r = 0; r < RPT; ++r) acc[r] = {0.f, 0.f, 0.f, 0.f};

    for (int kc = 0; kc < NKC; ++kc) {
        const float4* Wg = reinterpret_cast<const float4*>(W + kc * 16 * OUTC);
        #pragma unroll
        for (int i = tid; i < 16 * CG; i += 256) wS4[i] = Wg[i];
        {   // 256 threads = 64 rows x 4 float4
            int rr = tid >> 2, j = tid & 3;
            int row = row0 + rr;
            float4 v = {0.f, 0.f, 0.f, 0.f};
            if (row < NN) {
                int f4 = kc * 4 + j;
                if (SRC == 0) {
                    v = (f4 < 16) ? reinterpret_cast<const float4*>(X)[row * 16 + f4]
                                  : reinterpret_cast<const float4*>(Hm)[row * 16 + f4 - 16];
                } else if (SRC == 1) {
                    v = reinterpret_cast<const float4*>(X)[row * 16 + f4];
                } else {
                    v = reinterpret_cast<const float4*>(Hm)[row * 16 + f4];
                    unsigned int r0 = RUb[row * 64 + 2 * f4];
                    unsigned int r1 = RUb[row * 64 + 2 * f4 + 1];
                    v.x *= bf2f(r0 & 0xFFFFu); v.y *= bf2f(r0 >> 16);
                    v.z *= bf2f(r1 & 0xFFFFu); v.w *= bf2f(r1 >> 16);
                }
            }
            inS4[rr * 4 + j] = v;
        }
        __syncthreads();

        #pragma unroll
        for (int k8 = 0; k8 < 2; ++k8) {
            float4 wr[8];
            #pragma unroll
            for (int j = 0; j < 8; ++j) wr[j] = wS4[(k8 * 8 + j) * CG + cg];
            #pragma unroll
            for (int r = 0; r < RPT; ++r) {
                const int rr = rsub + r * RSTEP;
                float4 a0 = inS4[rr * 4 + k8 * 2];
                float4 a1 = inS4[rr * 4 + k8 * 2 + 1];
                acc[r].x += a0.x * wr[0].x; acc[r].y += a0.x * wr[0].y;
                acc[r].z += a0.x * wr[0].z; acc[r].w += a0.x * wr[0].w;
                acc[r].x += a0.y * wr[1].x; acc[r].y += a0.y * wr[1].y;
                acc[r].z += a0.y * wr[1].z; acc[r].w += a0.y * wr[1].w;
                acc[r].x += a0.z * wr[2].x; acc[r].y += a0.z * wr[2].y;
                acc[r].z += a0.z * wr[2].z; acc[r].w += a0.z * wr[2].w;
                acc[r].x += a0.w * wr[3].x; acc[r].y += a0.w * wr[3].y;
                acc[r].z += a0.w * wr[3].z; acc[r].w += a0.w * wr[3].w;
                acc[r].x += a1.x * wr[4].x; acc[r].y += a1.x * wr[4].y;
                acc[r].z += a1.x * wr[4].z; acc[r].w += a1.x * wr[4].w;
                acc[r].x += a1.y * wr[5].x; acc[r].y += a1.y * wr[5].y;
                acc[r].z += a1.y * wr[5].z; acc[r].w += a1.y * wr[5].w;
                acc[r].x += a1.z * wr[6].x; acc[r].y += a1.z * wr[6].y;
                acc[r].z += a1.z * wr[6].z; acc[r].w += a1.z * wr[6].w;
                acc[r].x += a1.w * wr[7].x; acc[r].y += a1.w * wr[7].y;
                acc[r].z += a1.w * wr[7].z; acc[r].w += a1.w * wr[7].w;
            }
        }
        __syncthreads();
    }

    #pragma unroll
    for (int r = 0; r < RPT; ++r) {
        int row = row0 + rsub + r * RSTEP;
        if (row < NN) {
            if (OMODE == 1) {
                reinterpret_cast<float4*>(outF)[(size_t)row * CG + cg] = acc[r];
            } else {
                float4 a = acc[r];
                if (OMODE == 2) {
                    float4 ad = reinterpret_cast<const float4*>(addF)[(size_t)row * CG + cg];
                    a.x += ad.x; a.y += ad.y; a.z += ad.z; a.w += ad.w;
                }
                uint2 o;
                o.x = f2bf(a.x) | (f2bf(a.y) << 16);
                o.y = f2bf(a.z) | (f2bf(a.w) << 16);
                outB[(size_t)row * CG + cg] = o;
            }
        }
    }
}

// ---------------- fused: prep ILP4 || gemm1 (Z1b) || gemm2a (X@W2top -> Z2p) ----------------
__launch_bounds__(256)
__global__ void k_build(const float* __restrict__ X, const float* __restrict__ Hm,
                        const float* __restrict__ W1, const float* __restrict__ W2,
                        uint2* __restrict__ Z1b, float* __restrict__ Z2p,
                        const int* __restrict__ dst, const float* __restrict__ w,
                        unsigned long long* __restrict__ packed,
                        int* __restrict__ edgePos) {
    __shared__ float4 wS4[512];    // 8KB
    __shared__ float4 inS4[256];   // 4KB
    const int bid = blockIdx.x;
    if (bid < PB) {
        const int base = bid * 1024 + threadIdx.x;
        #pragma unroll
        for (int k = 0; k < 4; ++k) {
            int e = base + k * 256;
            if (e < NE) {
                unsigned long long inc =
                    (1ULL << PACK_SHIFT) | (unsigned long long)(w[e] * 4294967296.0f);
                unsigned long long old = atomicAdd(&packed[dst[e]], inc);
                edgePos[e] = (int)(old >> PACK_SHIFT);
            }
        }
        return;
    }
    if (bid < PB + GB) {
        gemm_core<128, 8, 0, 0>(X, Hm, nullptr, W1, nullptr, Z1b, nullptr,
                                bid - PB, wS4, inS4);
        return;
    }
    gemm_core<64, 4, 1, 1>(X, Hm, nullptr, W2, nullptr, nullptr, Z2p,
                           bid - PB - GB, wS4, inS4);
}

// ---------------- gemm2b: Z2b = bf16( Z2p + (H*r)@W2bot ) ----------------
__launch_bounds__(256)
__global__ void k_gemm2b(const float* __restrict__ X, const float* __restrict__ Hm,
                         const unsigned int* __restrict__ RUb, const float* __restrict__ W2,
                         const float* __restrict__ Z2p, uint2* __restrict__ Z2b) {
    __shared__ float4 wS4[256];    // 4KB
    __shared__ float4 inS4[256];   // 4KB
    gemm_core<64, 4, 2, 2>(X, Hm, RUb, W2 + 64 * 64, Z2p, Z2b, nullptr,
                           blockIdx.x, wS4, inS4);
}

// ---------------- scan step 1: cnt + dinv from packed, chunk-local scan ----------------
__global__ void k_scan1(const unsigned long long* __restrict__ packed,
                        int* __restrict__ start, int* __restrict__ blockSums,
                        float* __restrict__ dinv) {
    __shared__ int lds[256];
    const int tid = threadIdx.x;
    const int idx = blockIdx.x * 256 + tid;
    int v = 0;
    if (idx < NN) {
        unsigned long long p = packed[idx];
        v = (int)(p >> PACK_SHIFT);
        float sumw = (float)((double)(p & PACK_MASK) * (1.0 / 4294967296.0));
        dinv[idx] = rsqrtf(1.0f + sumw);     // deg >= 1 (self loop)
    }
    lds[tid] = v;
    __syncthreads();
    #pragma unroll
    for (int off = 1; off < 256; off <<= 1) {
        int t = (tid >= off) ? lds[tid - off] : 0;
        __syncthreads();
        lds[tid] += t;
        __syncthreads();
    }
    if (idx < NN) start[idx] = lds[tid] - v;   // chunk-local exclusive
    if (tid == 255) blockSums[blockIdx.x] = lds[255];
}

// ---------------- scan steps 2+3 merged: each block reduces its prefix ----------------
__global__ void k_scan23(int* __restrict__ start, const int* __restrict__ blockSums) {
    __shared__ int lds[256];
    const int tid = threadIdx.x;
    const int b = blockIdx.x;
    lds[tid] = (tid < b) ? blockSums[tid] : 0;     // SCAN_B <= 256
    __syncthreads();
    #pragma unroll
    for (int off = 128; off > 0; off >>= 1) {
        if (tid < off) lds[tid] += lds[tid + off];
        __syncthreads();
    }
    const int off0 = lds[0];
    const int idx = b * 256 + tid;
    if (idx < NN) start[idx] += off0;
    if (b == 0 && tid == 0) start[NN] = NE;
}

// ---------------- CSR fill: atomic-free ILP4, packed (src | fp16 norm) ----------------
__global__ void k_fill(const int* __restrict__ src, const int* __restrict__ dst,
                       const float* __restrict__ w, const float* __restrict__ dinv,
                       const int* __restrict__ start, const int* __restrict__ edgePos,
                       unsigned int* __restrict__ snP) {
    const int base = blockIdx.x * 1024 + threadIdx.x;
    #pragma unroll
    for (int k = 0; k < 4; ++k) {
        int e = base + k * 256;
        if (e < NE) {
            int s = src[e], d = dst[e];
            float nm = dinv[s] * w[e] * dinv[d];
            unsigned int hn = __half_as_ushort(__float2half(nm));
            snP[start[d] + edgePos[e]] = (unsigned int)s | (hn << 16);
        }
    }
}

// ---------------- CSR gather, 8x unrolled + fused epilogue ----------------
// MODE 0 (conv1): RUb = bf16(sigmoid(agg + b1))   [NN x 128 bf16, packed uint2]
// MODE 1 (conv2): out = u*H + (1-u)*tanh(agg+b2)  [NN x 64 f32], u from RUb
template <int OUTC, int MODE>
__launch_bounds__(256)
__global__ void k_gather(const int* __restrict__ start, const unsigned int* __restrict__ snP,
                         const uint2* __restrict__ Zb, const float* __restrict__ dinv,
                         const float* __restrict__ bias, const uint2* __restrict__ RUb2,
                         uint2* __restrict__ outB, const float* __restrict__ Hm,
                         float* __restrict__ out) {
    constexpr int GRP = OUTC / 4;                 // lanes per node
    constexpr int NPB = 256 / GRP;                // nodes per block
    const int node = blockIdx.x * NPB + threadIdx.x / GRP;
    const int l = threadIdx.x % GRP;
    if (node >= NN) return;

    const int e0 = start[node], e1 = start[node + 1];

    float dn = dinv[node];
    dn = dn * dn;
    uint2 zs = Zb[(size_t)node * GRP + l];
    float4 acc;
    acc.x = bf2f(zs.x & 0xFFFFu) * dn;
    acc.y = bf2f(zs.x >> 16) * dn;
    acc.z = bf2f(zs.y & 0xFFFFu) * dn;
    acc.w = bf2f(zs.y >> 16) * dn;

    #define EFMA(Z, NM) \
        acc.x += bf2f((Z).x & 0xFFFFu) * (NM); \
        acc.y += bf2f((Z).x >> 16) * (NM);     \
        acc.z += bf2f((Z).y & 0xFFFFu) * (NM); \
        acc.w += bf2f((Z).y >> 16) * (NM);

    int e = e0;
    for (; e + 8 <= e1; e += 8) {
        unsigned sn0 = snP[e],     sn1 = snP[e + 1], sn2 = snP[e + 2], sn3 = snP[e + 3];
        unsigned sn4 = snP[e + 4], sn5 = snP[e + 5], sn6 = snP[e + 6], sn7 = snP[e + 7];
        uint2 z0 = Zb[(size_t)(sn0 & 0xFFFFu) * GRP + l];
        uint2 z1 = Zb[(size_t)(sn1 & 0xFFFFu) * GRP + l];
        uint2 z2 = Zb[(size_t)(sn2 & 0xFFFFu) * GRP + l];
        uint2 z3 = Zb[(size_t)(sn3 & 0xFFFFu) * GRP + l];
        uint2 z4 = Zb[(size_t)(sn4 & 0xFFFFu) * GRP + l];
        uint2 z5 = Zb[(size_t)(sn5 & 0xFFFFu) * GRP + l];
        uint2 z6 = Zb[(size_t)(sn6 & 0xFFFFu) * GRP + l];
        uint2 z7 = Zb[(size_t)(sn7 & 0xFFFFu) * GRP + l];
        float n0 = __half2float(__ushort_as_half((unsigned short)(sn0 >> 16)));
        float n1 = __half2float(__ushort_as_half((unsigned short)(sn1 >> 16)));
        float n2 = __half2float(__ushort_as_half((unsigned short)(sn2 >> 16)));
        float n3 = __half2float(__ushort_as_half((unsigned short)(sn3 >> 16)));
        float n4 = __half2float(__ushort_as_half((unsigned short)(sn4 >> 16)));
        float n5 = __half2float(__ushort_as_half((unsigned short)(sn5 >> 16)));
        float n6 = __half2float(__ushort_as_half((unsigned short)(sn6 >> 16)));
        float n7 = __half2float(__ushort_as_half((unsigned short)(sn7 >> 16)));
        EFMA(z0, n0) EFMA(z1, n1) EFMA(z2, n2) EFMA(z3, n3)
        EFMA(z4, n4) EFMA(z5, n5) EFMA(z6, n6) EFMA(z7, n7)
    }
    if (e + 4 <= e1) {
        unsigned sn0 = snP[e], sn1 = snP[e + 1], sn2 = snP[e + 2], sn3 = snP[e + 3];
        uint2 z0 = Zb[(size_t)(sn0 & 0xFFFFu) * GRP + l];
        uint2 z1 = Zb[(size_t)(sn1 & 0xFFFFu) * GRP + l];
        uint2 z2 = Zb[(size_t)(sn2 & 0xFFFFu) * GRP + l];
        uint2 z3 = Zb[(size_t)(sn3 & 0xFFFFu) * GRP + l];
        float n0 = __half2float(__ushort_as_half((unsigned short)(sn0 >> 16)));
        float n1 = __half2float(__ushort_as_half((unsigned short)(sn1 >> 16)));
        float n2 = __half2float(__ushort_as_half((unsigned short)(sn2 >> 16)));
        float n3 = __half2float(__ushort_as_half((unsigned short)(sn3 >> 16)));
        EFMA(z0, n0) EFMA(z1, n1) EFMA(z2, n2) EFMA(z3, n3)
        e += 4;
    }
    for (; e < e1; ++e) {
        unsigned sn = snP[e];
        float nm = __half2float(__ushort_as_half((unsigned short)(sn >> 16)));
        uint2 z = Zb[(size_t)(sn & 0xFFFFu) * GRP + l];
        EFMA(z, nm)
    }
    #undef EFMA

    const int c = l * 4;
    float4 bb = *reinterpret_cast<const float4*>(bias + c);
    acc.x += bb.x; acc.y += bb.y; acc.z += bb.z; acc.w += bb.w;

    if (MODE == 0) {
        float4 o;
        o.x = 1.f / (1.f + expf(-acc.x));
        o.y = 1.f / (1.f + expf(-acc.y));
        o.z = 1.f / (1.f + expf(-acc.z));
        o.w = 1.f / (1.f + expf(-acc.w));
        uint2 pk;
        pk.x = f2bf(o.x) | (f2bf(o.y) << 16);
        pk.y = f2bf(o.z) | (f2bf(o.w) << 16);
        outB[(size_t)node * 32 + l] = pk;
    } else {
        uint2 uu = RUb2[(size_t)node * 32 + 16 + l];
        float u0 = bf2f(uu.x & 0xFFFFu), u1 = bf2f(uu.x >> 16);
        float u2 = bf2f(uu.y & 0xFFFFu), u3 = bf2f(uu.y >> 16);
        float4 h4 = *reinterpret_cast<const float4*>(Hm + (size_t)node * 64 + c);
        float4 o;
        o.x = u0 * h4.x + (1.f - u0) * tanhf(acc.x);
        o.y = u1 * h4.y + (1.f - u1) * tanhf(acc.y);
        o.z = u2 * h4.z + (1.f - u2) * tanhf(acc.z);
        o.w = u3 * h4.w + (1.f - u3) * tanhf(acc.w);
        *reinterpret_cast<float4*>(out + (size_t)node * 64 + c) = o;
    }
}

extern "C" void kernel_launch(void* const* d_in, const int* in_sizes, int n_in,
                              void* d_out, int out_size, void* d_ws, size_t ws_size,
                              hipStream_t stream) {
    const float* X  = (const float*)d_in[0];
    const float* Hm = (const float*)d_in[1];
    const int*   ei = (const int*)d_in[2];           // [2][E]
    const float* w  = (const float*)d_in[3];
    const float* W1 = (const float*)d_in[4];         // [128][128]
    const float* b1 = (const float*)d_in[5];
    const float* W2 = (const float*)d_in[6];         // [128][64]
    const float* b2 = (const float*)d_in[7];
    float* out = (float*)d_out;

    const int* src = ei;
    const int* dst = ei + NE;

    // 8B-aligned chunks first
    char* p = (char*)d_ws;
    unsigned long long* packed = (unsigned long long*)p; p += sizeof(unsigned long long) * NN;
    uint2* Z1b       = (uint2*)p;  p += sizeof(uint2) * NN * 32;   // NN x 128 bf16
    uint2* Z2b       = (uint2*)p;  p += sizeof(uint2) * NN * 16;   // NN x 64 bf16
    uint2* RUb2      = (uint2*)p;  p += sizeof(uint2) * NN * 32;   // NN x 128 bf16
    float* Z2p       = (float*)p;  p += sizeof(float) * NN * 64;   // X@W2top f32
    float* dinv      = (float*)p;  p += sizeof(float) * NN;
    int*   start     = (int*)p;    p += sizeof(int) * (NN + 1);
    int*   blockSums = (int*)p;    p += sizeof(int) * 256;
    int*   edgePos   = (int*)p;    p += sizeof(int) * NE;
    unsigned int* snP = (unsigned int*)p; p += sizeof(unsigned int) * NE;

    // fused: prep atomics (ILP4) || gemm1 || gemm2a
    hipMemsetAsync(packed, 0, sizeof(unsigned long long) * NN, stream);
    k_build<<<PB + 2 * GB, 256, 0, stream>>>(X, Hm, W1, W2, Z1b, Z2p, dst, w,
                                             packed, edgePos);

    // CSR finalize
    k_scan1<<<SCAN_B, 256, 0, stream>>>(packed, start, blockSums, dinv);
    k_scan23<<<SCAN_B, 256, 0, stream>>>(start, blockSums);
    k_fill<<<PB, 256, 0, stream>>>(src, dst, w, dinv, start, edgePos, snP);

    // conv1 aggregate: RUb = bf16(sigmoid(S@Z1 + b1))
    k_gather<128, 0><<<(NN * 32 + 255) / 256, 256, 0, stream>>>(
        start, snP, Z1b, dinv, b1, nullptr, RUb2, nullptr, nullptr);

    // conv2: Z2b = bf16(Z2p + (H*r)@W2bot) ; out = u*H + (1-u)*tanh(S@Z2 + b2)
    k_gemm2b<<<GB, 256, 0, stream>>>(X, Hm, (const unsigned int*)RUb2, W2, Z2p, Z2b);
    k_gather<64, 1><<<(NN * 16 + 255) / 256, 256, 0, stream>>>(
        start, snP, Z2b, dinv, b2, RUb2, nullptr, Hm, out);
}